// Round 5
// baseline (659.725 us; speedup 1.0000x reference)
//
#include <hip/hip_runtime.h>
#include <hip/hip_bf16.h>
#include <math.h>

#define BB 16
#define SS 512
#define INDIM 64
#define DMODEL 64
#define HID 256
#define FILT 32
#define TYY 256
#define TXX 287
#define NT 5
#define RIDGEF 0.01f
#define THRESHF 0.005f

// ---------------------------------------------------------------------------
// Kernel 1: fused MLP -> layernorm -> tanh -> W2 -> tanh (e_orig, f32 out)
//           -> +pos-enc -> q, kT.  4 rows per block.
// ---------------------------------------------------------------------------
__global__ __launch_bounds__(256) void k_mlp(
    const float* __restrict__ fps, const float* __restrict__ W1, const float* __restrict__ b1,
    const float* __restrict__ gamma, const float* __restrict__ beta,
    const float* __restrict__ W2, const float* __restrict__ b2,
    const float* __restrict__ Wq, const float* __restrict__ bq,
    const float* __restrict__ Wk, const float* __restrict__ bk,
    float* __restrict__ e_out, float* __restrict__ q_out, float* __restrict__ kT_out)
{
    const int row0 = blockIdx.x << 2;
    const int tid = threadIdx.x;

    __shared__ float fr[4][INDIM];
    __shared__ float red[4][256];
    __shared__ float th4[4][HID];
    __shared__ float ee4[4][DMODEL];
    __shared__ float part4[4][4][DMODEL];
    __shared__ float partk4[4][4][DMODEL];

    { int r = tid >> 6, i = tid & 63;
      fr[r][i] = fps[(row0 + r) * INDIM + i]; }
    __syncthreads();

    float h[4];
    float b1v = b1[tid];
    #pragma unroll
    for (int r = 0; r < 4; ++r) h[r] = b1v;
    for (int i = 0; i < INDIM; ++i) {
        float w = W1[i * HID + tid];
        #pragma unroll
        for (int r = 0; r < 4; ++r) h[r] = fmaf(fr[r][i], w, h[r]);
    }

    #pragma unroll
    for (int r = 0; r < 4; ++r) red[r][tid] = h[r];
    __syncthreads();
    for (int off = 128; off > 0; off >>= 1) {
        if (tid < off) {
            #pragma unroll
            for (int r = 0; r < 4; ++r) red[r][tid] += red[r][tid + off];
        }
        __syncthreads();
    }
    float mu[4];
    #pragma unroll
    for (int r = 0; r < 4; ++r) mu[r] = red[r][0] * (1.0f / HID);
    __syncthreads();
    #pragma unroll
    for (int r = 0; r < 4; ++r) { float d = h[r] - mu[r]; red[r][tid] = d * d; }
    __syncthreads();
    for (int off = 128; off > 0; off >>= 1) {
        if (tid < off) {
            #pragma unroll
            for (int r = 0; r < 4; ++r) red[r][tid] += red[r][tid + off];
        }
        __syncthreads();
    }
    float gm = gamma[tid], bt = beta[tid];
    #pragma unroll
    for (int r = 0; r < 4; ++r) {
        float var = red[r][0] * (1.0f / HID);
        float hn = (h[r] - mu[r]) * rsqrtf(var + 1e-5f) * gm + bt;
        th4[r][tid] = tanhf(hn);
    }
    __syncthreads();

    { int p = tid >> 6, j = tid & 63;
      float acc[4] = {0.f, 0.f, 0.f, 0.f};
      for (int i = p * 64; i < p * 64 + 64; ++i) {
          float w = W2[i * DMODEL + j];
          #pragma unroll
          for (int r = 0; r < 4; ++r) acc[r] = fmaf(th4[r][i], w, acc[r]);
      }
      #pragma unroll
      for (int r = 0; r < 4; ++r) part4[p][r][j] = acc[r];
    }
    __syncthreads();
    { int r = tid >> 6, j = tid & 63;
      float e = part4[0][r][j] + part4[1][r][j] + part4[2][r][j] + part4[3][r][j] + b2[j];
      float eo = tanhf(e);
      int row = row0 + r;
      int s = row & (SS - 1);
      e_out[(size_t)row * DMODEL + j] = eo;                       // f32 store
      float div = expf(-(float)(j & ~1) * 0.14391156831212787f);  // ln(10000)/64
      float ang = (float)s * div;
      float pe = (j & 1) ? cosf(ang) : sinf(ang);
      ee4[r][j] = eo + 0.05f * pe;
    }
    __syncthreads();
    { int p = tid >> 6, j = tid & 63;
      float aq[4] = {0.f,0.f,0.f,0.f}, ak[4] = {0.f,0.f,0.f,0.f};
      for (int i = p * 16; i < p * 16 + 16; ++i) {
          float wqv = Wq[i * DMODEL + j];
          float wkv = Wk[i * DMODEL + j];
          #pragma unroll
          for (int r = 0; r < 4; ++r) {
              aq[r] = fmaf(ee4[r][i], wqv, aq[r]);
              ak[r] = fmaf(ee4[r][i], wkv, ak[r]);
          }
      }
      #pragma unroll
      for (int r = 0; r < 4; ++r) { part4[p][r][j] = aq[r]; partk4[p][r][j] = ak[r]; }
    }
    __syncthreads();
    { int r = tid >> 6, j = tid & 63;
      float qv = part4[0][r][j] + part4[1][r][j] + part4[2][r][j] + part4[3][r][j] + bq[j];
      float kv = partk4[0][r][j] + partk4[1][r][j] + partk4[2][r][j] + partk4[3][r][j] + bk[j];
      int row = row0 + r;
      int b = row >> 9, s = row & (SS - 1);
      q_out[(size_t)row * DMODEL + j] = qv;
      kT_out[(size_t)(b * DMODEL + j) * SS + s] = kv;
    }
}

// ---------------------------------------------------------------------------
// Kernel 2: causal scores + softmax(scale 2/sqrt(64)=0.25) -> alpha f32
// directly into d_out.  One block = 4 consecutive t-rows of one batch.
// ---------------------------------------------------------------------------
__global__ __launch_bounds__(256) void k_attn(
    const float* __restrict__ q, const float* __restrict__ kT,
    float* __restrict__ alpha)
{
    const int blk = blockIdx.x;
    const int b = blk >> 7;
    const int t0 = (blk & 127) << 2;
    const int t3 = t0 + 3;
    const int tid = threadIdx.x;
    const int wave = tid >> 6, lane = tid & 63;

    __shared__ float qt[4 * DMODEL];
    __shared__ float redm[4][4];

    qt[tid] = q[(size_t)(b * SS + t0 + (tid >> 6)) * DMODEL + (tid & 63)];
    __syncthreads();

    const float* kTb = kT + (size_t)b * DMODEL * SS;
    const int s0 = tid, s1 = tid + 256;
    float a0[4] = {0,0,0,0}, a1[4] = {0,0,0,0};
    if (s1 <= t3) {
        for (int d = 0; d < DMODEL; ++d) {
            float k0 = kTb[d * SS + s0];
            float k1 = kTb[d * SS + s1];
            #pragma unroll
            for (int r = 0; r < 4; ++r) {
                float qv = qt[r * DMODEL + d];
                a0[r] = fmaf(qv, k0, a0[r]);
                a1[r] = fmaf(qv, k1, a1[r]);
            }
        }
    } else if (s0 <= t3) {
        for (int d = 0; d < DMODEL; ++d) {
            float k0 = kTb[d * SS + s0];
            #pragma unroll
            for (int r = 0; r < 4; ++r) a0[r] = fmaf(qt[r * DMODEL + d], k0, a0[r]);
        }
    }
    float lg0[4], lg1[4];
    #pragma unroll
    for (int r = 0; r < 4; ++r) {
        int tr = t0 + r;
        lg0[r] = (s0 <= tr) ? 0.25f * a0[r] : -INFINITY;
        lg1[r] = (s1 <= tr) ? 0.25f * a1[r] : -INFINITY;
    }
    float mr[4];
    #pragma unroll
    for (int r = 0; r < 4; ++r) {
        float m = fmaxf(lg0[r], lg1[r]);
        #pragma unroll
        for (int off = 32; off > 0; off >>= 1) m = fmaxf(m, __shfl_xor(m, off));
        if (lane == 0) redm[r][wave] = m;
    }
    __syncthreads();
    #pragma unroll
    for (int r = 0; r < 4; ++r)
        mr[r] = fmaxf(fmaxf(redm[r][0], redm[r][1]), fmaxf(redm[r][2], redm[r][3]));
    __syncthreads();
    float ex0[4], ex1[4], sr[4];
    #pragma unroll
    for (int r = 0; r < 4; ++r) {
        ex0[r] = expf(lg0[r] - mr[r]);   // exp(-inf) = 0 for masked
        ex1[r] = expf(lg1[r] - mr[r]);
        float sm = ex0[r] + ex1[r];
        #pragma unroll
        for (int off = 32; off > 0; off >>= 1) sm += __shfl_xor(sm, off);
        if (lane == 0) redm[r][wave] = sm;
    }
    __syncthreads();
    #pragma unroll
    for (int r = 0; r < 4; ++r)
        sr[r] = redm[r][0] + redm[r][1] + redm[r][2] + redm[r][3];
    #pragma unroll
    for (int r = 0; r < 4; ++r) {
        float inv = 1.0f / sr[r];
        size_t base = (size_t)(b * SS + t0 + r) * SS;
        alpha[base + s0] = ex0[r] * inv;
        alpha[base + s1] = ex1[r] * inv;
    }
}

// ---------------------------------------------------------------------------
// Kernel 3: ONE block per (b,t): threshold this row's f32 alpha (read straight
// from d_out), compact passing s, accumulate wm-weighted Gram via the
// sliding-diagonal recurrence in LDS, Cholesky solve, prediction loss.
// ---------------------------------------------------------------------------
__global__ __launch_bounds__(256) void k_bt(
    const float* __restrict__ x, const float* __restrict__ y,
    const int* __restrict__ steps, const float* __restrict__ alpha,
    float* __restrict__ lossbt, int* __restrict__ valid)
{
    const int g = blockIdx.x;
    const int b = g / NT, t = g % NT;
    const int tid = threadIdx.x;

    __shared__ float wrow[SS];
    __shared__ int slist[SS];
    __shared__ int scount;
    __shared__ float gloc[1056];       // 1024 gram + 32 cross
    __shared__ float Gs[1056];
    __shared__ float xs[TXX + 1];
    __shared__ float ys[TYY];
    __shared__ float A[FILT][FILT + 1];
    __shared__ float z[FILT];
    __shared__ float wt[FILT];
    __shared__ float red[256];
    __shared__ int step_s;

    if (tid == 0) { scount = 0; step_s = steps[t]; }
    for (int idx = tid; idx < 1056; idx += 256) gloc[idx] = 0.f;
    __syncthreads();

    // f32 alpha row of this (b, step): exact reference threshold semantics
    const float* arow = alpha + (size_t)(b * SS + step_s) * SS;
    #pragma unroll
    for (int hh = 0; hh < 2; ++hh) {
        int s = tid + hh * 256;
        float a = arow[s];
        float w = (a > THRESHF) ? a : 0.f;
        wrow[s] = w;
        if (w > 0.f) { int pos = atomicAdd(&scount, 1); slist[pos] = s; }
    }
    __syncthreads();
    const int nsel = scount;

    for (int it = 0; it < nsel; ++it) {
        const int s = slist[it];
        const float w = wrow[s];
        const float* xr = x + (size_t)(b * SS + s) * TXX;
        const float* yr = y + (size_t)(b * SS + s) * TYY;
        for (int i = tid; i < TXX; i += 256) xs[i] = xr[i];
        ys[tid] = yr[tid];
        __syncthreads();

        // C[l] = sum_k x[k+l] y[k]   (8 lanes per lag, shuffle merge)
        { int l = tid >> 3, p = tid & 7;
          float c = 0.f;
          for (int k = p * 32; k < p * 32 + 32; ++k) c = fmaf(xs[k + l], ys[k], c);
          c += __shfl_xor(c, 1); c += __shfl_xor(c, 2); c += __shfl_xor(c, 4);
          if (p == 0) Gs[1024 + l] = c;
        }
        // G[0][d] full dot, then sliding recurrence along diagonal d
        { int d = tid >> 3, p = tid & 7;
          float a = 0.f;
          for (int k = p * 32; k < p * 32 + 32; ++k) a = fmaf(xs[k], xs[k + d], a);
          a += __shfl_xor(a, 1); a += __shfl_xor(a, 2); a += __shfl_xor(a, 4);
          if (p == 0) {
              Gs[d] = a;
              Gs[d * 32] = a;
              for (int l = 1; l < FILT - d; ++l) {
                  a = fmaf(xs[l + 255], xs[l + 255 + d], a);
                  a = fmaf(-xs[l - 1], xs[l - 1 + d], a);
                  Gs[l * 32 + l + d] = a;
                  Gs[(l + d) * 32 + l] = a;
              }
          }
        }
        __syncthreads();
        for (int idx = tid; idx < 1056; idx += 256)
            gloc[idx] = fmaf(w, Gs[idx], gloc[idx]);
        __syncthreads();
    }

    // gram -> A (+ridge), cross -> z
    for (int idx = tid; idx < 1024; idx += 256) {
        int i = idx >> 5, j = idx & 31;
        A[i][j] = gloc[idx] + ((i == j) ? RIDGEF : 0.f);
    }
    if (tid < FILT) z[tid] = gloc[1024 + tid];
    __syncthreads();

    // Cholesky (lower)
    for (int k = 0; k < FILT; ++k) {
        if (tid == 0) A[k][k] = sqrtf(A[k][k]);
        __syncthreads();
        if (tid > k && tid < FILT) A[tid][k] /= A[k][k];
        __syncthreads();
        for (int idx = tid; idx < 1024; idx += 256) {
            int i = idx >> 5, j = idx & 31;
            if (i > k && j > k && j <= i) A[i][j] -= A[i][k] * A[j][k];
        }
        __syncthreads();
    }
    for (int k = 0; k < FILT; ++k) {
        if (tid == 0) z[k] /= A[k][k];
        __syncthreads();
        if (tid > k && tid < FILT) z[tid] -= A[tid][k] * z[k];
        __syncthreads();
    }
    for (int k = FILT - 1; k >= 0; --k) {
        if (tid == 0) wt[k] = z[k] / A[k][k];
        __syncthreads();
        if (tid < k) z[tid] -= A[k][tid] * wt[k];
        __syncthreads();
    }

    // pred + per-(b,t) loss
    const int sstep = step_s;
    const float* xrow = x + (size_t)(b * SS + sstep) * TXX;
    for (int i = tid; i < TXX; i += 256) xs[i] = xrow[i];
    __syncthreads();
    float pk = 0.f;
    #pragma unroll
    for (int l = 0; l < FILT; ++l) pk = fmaf(xs[tid + l], wt[l], pk);
    float d = y[(size_t)(b * SS + sstep) * TYY + tid] - pk;
    red[tid] = d * d;
    __syncthreads();
    for (int off = 128; off > 0; off >>= 1) {
        if (tid < off) red[tid] += red[tid + off];
        __syncthreads();
    }
    if (tid == 0) {
        lossbt[g] = red[0] * (1.0f / TYY);
        valid[g] = (nsel > 0) ? 1 : 0;
    }
}

// ---------------------------------------------------------------------------
// Kernel 4: final masked mean -> out[0] (f32)
// ---------------------------------------------------------------------------
__global__ __launch_bounds__(128) void k_final(
    const float* __restrict__ lossbt, const int* __restrict__ valid,
    float* __restrict__ out0)
{
    __shared__ float rs[128];
    __shared__ int rc[128];
    int tid = threadIdx.x;
    float v = 0.f; int c = 0;
    if (tid < BB * NT && valid[tid]) { v = lossbt[tid]; c = 1; }
    rs[tid] = v; rc[tid] = c;
    __syncthreads();
    for (int off = 64; off > 0; off >>= 1) {
        if (tid < off) { rs[tid] += rs[tid + off]; rc[tid] += rc[tid + off]; }
        __syncthreads();
    }
    if (tid == 0) {
        int n = rc[0] > 0 ? rc[0] : 1;
        out0[0] = rs[0] / (float)n;
    }
}

extern "C" void kernel_launch(void* const* d_in, const int* in_sizes, int n_in,
                              void* d_out, int out_size, void* d_ws, size_t ws_size,
                              hipStream_t stream)
{
    const float* fps  = (const float*)d_in[0];
    const float* x    = (const float*)d_in[1];
    const float* y    = (const float*)d_in[2];
    const int* steps  = (const int*)d_in[3];
    const float* W1   = (const float*)d_in[4];
    const float* b1   = (const float*)d_in[5];
    const float* gamma= (const float*)d_in[6];
    const float* beta = (const float*)d_in[7];
    const float* W2   = (const float*)d_in[8];
    const float* b2   = (const float*)d_in[9];
    const float* Wq   = (const float*)d_in[10];
    const float* bq   = (const float*)d_in[11];
    const float* Wk   = (const float*)d_in[12];
    const float* bk   = (const float*)d_in[13];

    // Output is FLOAT32 (reference outputs are f32; R0-R4 forensics confirm).
    // Flat layout, return order: [loss(1) | alpha(B*S*S) | e_orig(B*S*D)]
    float* out   = (float*)d_out;
    float* alpha = out + 1;
    float* e_out = out + 1 + (size_t)BB * SS * SS;

    float* q      = (float*)d_ws;                              // B*S*64
    float* kT     = q + (size_t)BB * SS * DMODEL;              // B*64*S
    float* lossbt = kT + (size_t)BB * DMODEL * SS;             // 80
    int*   valid  = (int*)(lossbt + 128);                      // 80

    hipLaunchKernelGGL(k_mlp, dim3(BB * SS / 4), dim3(256), 0, stream,
                       fps, W1, b1, gamma, beta, W2, b2, Wq, bq, Wk, bk,
                       e_out, q, kT);
    hipLaunchKernelGGL(k_attn, dim3(BB * (SS / 4)), dim3(256), 0, stream,
                       q, kT, alpha);
    hipLaunchKernelGGL(k_bt, dim3(BB * NT), dim3(256), 0, stream,
                       x, y, steps, alpha, lossbt, valid);
    hipLaunchKernelGGL(k_final, dim3(1), dim3(128), 0, stream, lossbt, valid, out);
}

// Round 6
// 246.958 us; speedup vs baseline: 2.6714x; 2.6714x over previous
//
#include <hip/hip_runtime.h>
#include <hip/hip_bf16.h>
#include <math.h>

#define BB 16
#define SS 512
#define INDIM 64
#define DMODEL 64
#define HID 256
#define FILT 32
#define TYY 256
#define TXX 287
#define NT 5
#define RIDGEF 0.01f
#define THRESHF 0.005f

// ---------------------------------------------------------------------------
// Kernel 1: fused MLP -> layernorm -> tanh -> W2 -> tanh (e_orig, f32 out)
//           -> +pos-enc -> q, kT.  4 rows per block.  (unchanged, verified)
// ---------------------------------------------------------------------------
__global__ __launch_bounds__(256) void k_mlp(
    const float* __restrict__ fps, const float* __restrict__ W1, const float* __restrict__ b1,
    const float* __restrict__ gamma, const float* __restrict__ beta,
    const float* __restrict__ W2, const float* __restrict__ b2,
    const float* __restrict__ Wq, const float* __restrict__ bq,
    const float* __restrict__ Wk, const float* __restrict__ bk,
    float* __restrict__ e_out, float* __restrict__ q_out, float* __restrict__ kT_out)
{
    const int row0 = blockIdx.x << 2;
    const int tid = threadIdx.x;

    __shared__ float fr[4][INDIM];
    __shared__ float red[4][256];
    __shared__ float th4[4][HID];
    __shared__ float ee4[4][DMODEL];
    __shared__ float part4[4][4][DMODEL];
    __shared__ float partk4[4][4][DMODEL];

    { int r = tid >> 6, i = tid & 63;
      fr[r][i] = fps[(row0 + r) * INDIM + i]; }
    __syncthreads();

    float h[4];
    float b1v = b1[tid];
    #pragma unroll
    for (int r = 0; r < 4; ++r) h[r] = b1v;
    for (int i = 0; i < INDIM; ++i) {
        float w = W1[i * HID + tid];
        #pragma unroll
        for (int r = 0; r < 4; ++r) h[r] = fmaf(fr[r][i], w, h[r]);
    }

    #pragma unroll
    for (int r = 0; r < 4; ++r) red[r][tid] = h[r];
    __syncthreads();
    for (int off = 128; off > 0; off >>= 1) {
        if (tid < off) {
            #pragma unroll
            for (int r = 0; r < 4; ++r) red[r][tid] += red[r][tid + off];
        }
        __syncthreads();
    }
    float mu[4];
    #pragma unroll
    for (int r = 0; r < 4; ++r) mu[r] = red[r][0] * (1.0f / HID);
    __syncthreads();
    #pragma unroll
    for (int r = 0; r < 4; ++r) { float d = h[r] - mu[r]; red[r][tid] = d * d; }
    __syncthreads();
    for (int off = 128; off > 0; off >>= 1) {
        if (tid < off) {
            #pragma unroll
            for (int r = 0; r < 4; ++r) red[r][tid] += red[r][tid + off];
        }
        __syncthreads();
    }
    float gm = gamma[tid], bt = beta[tid];
    #pragma unroll
    for (int r = 0; r < 4; ++r) {
        float var = red[r][0] * (1.0f / HID);
        float hn = (h[r] - mu[r]) * rsqrtf(var + 1e-5f) * gm + bt;
        th4[r][tid] = tanhf(hn);
    }
    __syncthreads();

    { int p = tid >> 6, j = tid & 63;
      float acc[4] = {0.f, 0.f, 0.f, 0.f};
      for (int i = p * 64; i < p * 64 + 64; ++i) {
          float w = W2[i * DMODEL + j];
          #pragma unroll
          for (int r = 0; r < 4; ++r) acc[r] = fmaf(th4[r][i], w, acc[r]);
      }
      #pragma unroll
      for (int r = 0; r < 4; ++r) part4[p][r][j] = acc[r];
    }
    __syncthreads();
    { int r = tid >> 6, j = tid & 63;
      float e = part4[0][r][j] + part4[1][r][j] + part4[2][r][j] + part4[3][r][j] + b2[j];
      float eo = tanhf(e);
      int row = row0 + r;
      int s = row & (SS - 1);
      e_out[(size_t)row * DMODEL + j] = eo;
      float div = expf(-(float)(j & ~1) * 0.14391156831212787f);  // ln(10000)/64
      float ang = (float)s * div;
      float pe = (j & 1) ? cosf(ang) : sinf(ang);
      ee4[r][j] = eo + 0.05f * pe;
    }
    __syncthreads();
    { int p = tid >> 6, j = tid & 63;
      float aq[4] = {0.f,0.f,0.f,0.f}, ak[4] = {0.f,0.f,0.f,0.f};
      for (int i = p * 16; i < p * 16 + 16; ++i) {
          float wqv = Wq[i * DMODEL + j];
          float wkv = Wk[i * DMODEL + j];
          #pragma unroll
          for (int r = 0; r < 4; ++r) {
              aq[r] = fmaf(ee4[r][i], wqv, aq[r]);
              ak[r] = fmaf(ee4[r][i], wkv, ak[r]);
          }
      }
      #pragma unroll
      for (int r = 0; r < 4; ++r) { part4[p][r][j] = aq[r]; partk4[p][r][j] = ak[r]; }
    }
    __syncthreads();
    { int r = tid >> 6, j = tid & 63;
      float qv = part4[0][r][j] + part4[1][r][j] + part4[2][r][j] + part4[3][r][j] + bq[j];
      float kv = partk4[0][r][j] + partk4[1][r][j] + partk4[2][r][j] + partk4[3][r][j] + bk[j];
      int row = row0 + r;
      int b = row >> 9, s = row & (SS - 1);
      q_out[(size_t)row * DMODEL + j] = qv;
      kT_out[(size_t)(b * DMODEL + j) * SS + s] = kv;
    }
}

// ---------------------------------------------------------------------------
// Kernel 2: causal scores + softmax -> alpha f32 into d_out.  (unchanged)
// ---------------------------------------------------------------------------
__global__ __launch_bounds__(256) void k_attn(
    const float* __restrict__ q, const float* __restrict__ kT,
    float* __restrict__ alpha)
{
    const int blk = blockIdx.x;
    const int b = blk >> 7;
    const int t0 = (blk & 127) << 2;
    const int t3 = t0 + 3;
    const int tid = threadIdx.x;
    const int wave = tid >> 6, lane = tid & 63;

    __shared__ float qt[4 * DMODEL];
    __shared__ float redm[4][4];

    qt[tid] = q[(size_t)(b * SS + t0 + (tid >> 6)) * DMODEL + (tid & 63)];
    __syncthreads();

    const float* kTb = kT + (size_t)b * DMODEL * SS;
    const int s0 = tid, s1 = tid + 256;
    float a0[4] = {0,0,0,0}, a1[4] = {0,0,0,0};
    if (s1 <= t3) {
        for (int d = 0; d < DMODEL; ++d) {
            float k0 = kTb[d * SS + s0];
            float k1 = kTb[d * SS + s1];
            #pragma unroll
            for (int r = 0; r < 4; ++r) {
                float qv = qt[r * DMODEL + d];
                a0[r] = fmaf(qv, k0, a0[r]);
                a1[r] = fmaf(qv, k1, a1[r]);
            }
        }
    } else if (s0 <= t3) {
        for (int d = 0; d < DMODEL; ++d) {
            float k0 = kTb[d * SS + s0];
            #pragma unroll
            for (int r = 0; r < 4; ++r) a0[r] = fmaf(qt[r * DMODEL + d], k0, a0[r]);
        }
    }
    float lg0[4], lg1[4];
    #pragma unroll
    for (int r = 0; r < 4; ++r) {
        int tr = t0 + r;
        lg0[r] = (s0 <= tr) ? 0.25f * a0[r] : -INFINITY;
        lg1[r] = (s1 <= tr) ? 0.25f * a1[r] : -INFINITY;
    }
    float mr[4];
    #pragma unroll
    for (int r = 0; r < 4; ++r) {
        float m = fmaxf(lg0[r], lg1[r]);
        #pragma unroll
        for (int off = 32; off > 0; off >>= 1) m = fmaxf(m, __shfl_xor(m, off));
        if (lane == 0) redm[r][wave] = m;
    }
    __syncthreads();
    #pragma unroll
    for (int r = 0; r < 4; ++r)
        mr[r] = fmaxf(fmaxf(redm[r][0], redm[r][1]), fmaxf(redm[r][2], redm[r][3]));
    __syncthreads();
    float ex0[4], ex1[4], sr[4];
    #pragma unroll
    for (int r = 0; r < 4; ++r) {
        ex0[r] = expf(lg0[r] - mr[r]);
        ex1[r] = expf(lg1[r] - mr[r]);
        float sm = ex0[r] + ex1[r];
        #pragma unroll
        for (int off = 32; off > 0; off >>= 1) sm += __shfl_xor(sm, off);
        if (lane == 0) redm[r][wave] = sm;
    }
    __syncthreads();
    #pragma unroll
    for (int r = 0; r < 4; ++r)
        sr[r] = redm[r][0] + redm[r][1] + redm[r][2] + redm[r][3];
    #pragma unroll
    for (int r = 0; r < 4; ++r) {
        float inv = 1.0f / sr[r];
        size_t base = (size_t)(b * SS + t0 + r) * SS;
        alpha[base + s0] = ex0[r] * inv;
        alpha[base + s1] = ex1[r] * inv;
    }
}

// ---------------------------------------------------------------------------
// Kernel 3 (stage 1): per (b, s-chunk) block.  Computes G_s once per selected
// s (sliding-diagonal recurrence, pitch-33 => no 32-way mirror conflicts),
// shares it across the 5 sample steps via per-t LDS accumulators, writes
// coalesced per-chunk partials (no atomics).  Register prefetch of next x/y.
// ---------------------------------------------------------------------------
__global__ __launch_bounds__(256) void k_gpart(
    const float* __restrict__ x, const float* __restrict__ y,
    const int* __restrict__ steps, const float* __restrict__ alpha,
    float* __restrict__ part, int C, int CS)
{
    const int b = blockIdx.x / C;
    const int chunk = blockIdx.x % C;
    const int tid = threadIdx.x;

    __shared__ float xs[288];
    __shared__ float ys[256];
    __shared__ float Gs[1056];        // 32x33 (pitch 33)
    __shared__ float crossL[32];
    __shared__ float acc[NT * 1088];  // per-t: 1056 gram(p33) + 32 cross
    __shared__ float wv[NT * 64];     // CS <= 64
    __shared__ int sl[64];
    __shared__ int nselS;
    __shared__ int stS[NT];
    __shared__ float redA[4][33];
    __shared__ float redB[4][33];

    if (tid < NT) stS[tid] = steps[tid];
    for (int idx = tid; idx < NT * 1088; idx += 256) acc[idx] = 0.f;
    if (tid < 32) Gs[tid * 33 + 32] = 0.f;   // pad column stays zero
    __syncthreads();

    // thresholded weights for this chunk's s range, all 5 sample rows
    for (int idx = tid; idx < NT * CS; idx += 256) {
        int t = idx / CS, si = idx % CS;
        float a = alpha[(size_t)(b * SS + stS[t]) * SS + chunk * CS + si];
        wv[t * 64 + si] = (a > THRESHF) ? a : 0.f;
    }
    __syncthreads();
    if (tid == 0) {
        int c = 0;
        for (int si = 0; si < CS; ++si) {
            float m = wv[si] + wv[64 + si] + wv[128 + si] + wv[192 + si] + wv[256 + si];
            if (m > 0.f) sl[c++] = si;
        }
        nselS = c;
    }
    __syncthreads();
    const int nsel = nselS;

    // register prefetch of first selected row
    float rx0 = 0.f, rx1 = 0.f, ry = 0.f;
    if (nsel > 0) {
        int sg = chunk * CS + sl[0];
        const float* xr = x + (size_t)(b * SS + sg) * TXX;
        const float* yr = y + (size_t)(b * SS + sg) * TYY;
        rx0 = xr[tid];
        if (tid < 31) rx1 = xr[256 + tid];
        ry = yr[tid];
    }

    for (int i = 0; i < nsel; ++i) {
        __syncthreads();                       // previous iter done with xs/ys
        xs[tid] = rx0;
        if (tid < 31) xs[256 + tid] = rx1;
        ys[tid] = ry;
        const int sl_cur = sl[i];
        __syncthreads();

        if (i + 1 < nsel) {                    // prefetch next selected row
            int sg = chunk * CS + sl[i + 1];
            const float* xr = x + (size_t)(b * SS + sg) * TXX;
            const float* yr = y + (size_t)(b * SS + sg) * TYY;
            rx0 = xr[tid];
            if (tid < 31) rx1 = xr[256 + tid];
            ry = yr[tid];
        }

        // C[l] and G0[d=l]: l=tid&31 (stride-1), p=tid>>5 (k partition)
        { int l = tid & 31, p = tid >> 5;
          float c = 0.f, a = 0.f;
          const int k0 = p * 32;
          #pragma unroll
          for (int kk = 0; kk < 32; ++kk) {
              int k = k0 + kk;
              float xv = xs[k + l];
              c = fmaf(xv, ys[k], c);
              a = fmaf(xs[k], xv, a);
          }
          c += __shfl_xor(c, 32);
          a += __shfl_xor(a, 32);
          int w = tid >> 6, lane = tid & 63;
          if (lane < 32) { redA[w][l] = c; redB[w][l] = a; }
        }
        __syncthreads();
        if (tid < 32) {
            float cfin = redA[0][tid] + redA[1][tid] + redA[2][tid] + redA[3][tid];
            float afin = redB[0][tid] + redB[1][tid] + redB[2][tid] + redB[3][tid];
            crossL[tid] = cfin;
            const int d = tid;
            float a = afin;
            Gs[d] = a;             // (0, d)
            Gs[d * 33] = a;        // (d, 0) mirror — pitch 33 => conflict-free
            for (int l = 1; l < FILT - d; ++l) {
                a = fmaf(xs[l + 255], xs[l + 255 + d], a);
                a = fmaf(-xs[l - 1], xs[l - 1 + d], a);
                Gs[l * 33 + l + d] = a;
                Gs[(l + d) * 33 + l] = a;
            }
        }
        __syncthreads();

        #pragma unroll
        for (int t = 0; t < NT; ++t) {
            float w = wv[t * 64 + sl_cur];
            if (w > 0.f) {
                for (int idx = tid; idx < 1088; idx += 256) {
                    float g = (idx < 1056) ? Gs[idx] : crossL[idx - 1056];
                    acc[t * 1088 + idx] = fmaf(w, g, acc[t * 1088 + idx]);
                }
            }
        }
    }
    __syncthreads();

    // coalesced partial store (zeros included)
    #pragma unroll
    for (int t = 0; t < NT; ++t) {
        size_t base = (size_t)((b * NT + t) * C + chunk) * 1088;
        for (int idx = tid; idx < 1088; idx += 256)
            part[base + idx] = acc[t * 1088 + idx];
    }
}

// ---------------------------------------------------------------------------
// Kernel 4 (stage 2): per (b,t): sum chunk partials, +ridge, Cholesky solve,
// prediction loss, valid flag (from f32 alpha row directly).
// ---------------------------------------------------------------------------
__global__ __launch_bounds__(256) void k_solve2(
    const float* __restrict__ x, const float* __restrict__ y,
    const int* __restrict__ steps, const float* __restrict__ alpha,
    const float* __restrict__ part,
    float* __restrict__ lossbt, int* __restrict__ valid, int C)
{
    const int g = blockIdx.x;
    const int b = g / NT, t = g % NT;
    const int tid = threadIdx.x;

    __shared__ float Af[1056];   // pitch 33
    __shared__ float z[FILT];
    __shared__ float wt[FILT];
    __shared__ float xs[TXX + 1];
    __shared__ float red[256];
    __shared__ int step_s;
    __shared__ int anyv;

    if (tid == 0) { step_s = steps[t]; anyv = 0; }
    __syncthreads();

    // sum chunk partials (coalesced, 5 independent accumulators)
    float a0 = 0.f, a1 = 0.f, a2 = 0.f, a3 = 0.f, a4 = 0.f;
    for (int ch = 0; ch < C; ++ch) {
        const float* pp = part + (size_t)(g * C + ch) * 1088;
        a0 += pp[tid];
        a1 += pp[tid + 256];
        a2 += pp[tid + 512];
        a3 += pp[tid + 768];
        if (tid < 64) a4 += pp[tid + 1024];
    }
    Af[tid] = a0; Af[tid + 256] = a1; Af[tid + 512] = a2; Af[tid + 768] = a3;
    if (tid < 32) Af[1024 + tid] = a4;          // gram row 31 tail
    else if (tid < 64) z[tid - 32] = a4;        // cross

    // valid flag from the f32 alpha row (exact reference semantics)
    { const float* arow = alpha + (size_t)(b * SS + step_s) * SS;
      if (arow[tid] > THRESHF || arow[tid + 256] > THRESHF) anyv = 1; }
    __syncthreads();
    if (tid < 32) Af[tid * 33 + tid] += RIDGEF;
    __syncthreads();

    // Cholesky (lower), pitch 33
    for (int k = 0; k < FILT; ++k) {
        if (tid == 0) Af[k * 33 + k] = sqrtf(Af[k * 33 + k]);
        __syncthreads();
        if (tid > k && tid < FILT) Af[tid * 33 + k] /= Af[k * 33 + k];
        __syncthreads();
        for (int idx = tid; idx < 1024; idx += 256) {
            int i = idx >> 5, j = idx & 31;
            if (i > k && j > k && j <= i) Af[i * 33 + j] -= Af[i * 33 + k] * Af[j * 33 + k];
        }
        __syncthreads();
    }
    for (int k = 0; k < FILT; ++k) {
        if (tid == 0) z[k] /= Af[k * 33 + k];
        __syncthreads();
        if (tid > k && tid < FILT) z[tid] -= Af[tid * 33 + k] * z[k];
        __syncthreads();
    }
    for (int k = FILT - 1; k >= 0; --k) {
        if (tid == 0) wt[k] = z[k] / Af[k * 33 + k];
        __syncthreads();
        if (tid < k) z[tid] -= Af[k * 33 + tid] * wt[k];
        __syncthreads();
    }

    // pred + per-(b,t) loss
    const int sstep = step_s;
    const float* xrow = x + (size_t)(b * SS + sstep) * TXX;
    for (int i = tid; i < TXX; i += 256) xs[i] = xrow[i];
    __syncthreads();
    float pk = 0.f;
    #pragma unroll
    for (int l = 0; l < FILT; ++l) pk = fmaf(xs[tid + l], wt[l], pk);
    float d = y[(size_t)(b * SS + sstep) * TYY + tid] - pk;
    red[tid] = d * d;
    __syncthreads();
    for (int off = 128; off > 0; off >>= 1) {
        if (tid < off) red[tid] += red[tid + off];
        __syncthreads();
    }
    if (tid == 0) {
        lossbt[g] = red[0] * (1.0f / TYY);
        valid[g] = anyv;
    }
}

// ---------------------------------------------------------------------------
// Kernel 5: final masked mean -> out[0] (f32)
// ---------------------------------------------------------------------------
__global__ __launch_bounds__(128) void k_final(
    const float* __restrict__ lossbt, const int* __restrict__ valid,
    float* __restrict__ out0)
{
    __shared__ float rs[128];
    __shared__ int rc[128];
    int tid = threadIdx.x;
    float v = 0.f; int c = 0;
    if (tid < BB * NT && valid[tid]) { v = lossbt[tid]; c = 1; }
    rs[tid] = v; rc[tid] = c;
    __syncthreads();
    for (int off = 64; off > 0; off >>= 1) {
        if (tid < off) { rs[tid] += rs[tid + off]; rc[tid] += rc[tid + off]; }
        __syncthreads();
    }
    if (tid == 0) {
        int n = rc[0] > 0 ? rc[0] : 1;
        out0[0] = rs[0] / (float)n;
    }
}

extern "C" void kernel_launch(void* const* d_in, const int* in_sizes, int n_in,
                              void* d_out, int out_size, void* d_ws, size_t ws_size,
                              hipStream_t stream)
{
    const float* fps  = (const float*)d_in[0];
    const float* x    = (const float*)d_in[1];
    const float* y    = (const float*)d_in[2];
    const int* steps  = (const int*)d_in[3];
    const float* W1   = (const float*)d_in[4];
    const float* b1   = (const float*)d_in[5];
    const float* gamma= (const float*)d_in[6];
    const float* beta = (const float*)d_in[7];
    const float* W2   = (const float*)d_in[8];
    const float* b2   = (const float*)d_in[9];
    const float* Wq   = (const float*)d_in[10];
    const float* bq   = (const float*)d_in[11];
    const float* Wk   = (const float*)d_in[12];
    const float* bk   = (const float*)d_in[13];

    // Output f32 flat: [loss(1) | alpha(B*S*S) | e_orig(B*S*D)]
    float* out   = (float*)d_out;
    float* alpha = out + 1;
    float* e_out = out + 1 + (size_t)BB * SS * SS;

    // ws: [lossbt(128) | valid(128 ints) | shared region]
    // shared region: q+kT during mlp/attn; chunk partials afterwards (aliased —
    // stream order guarantees q/kT are dead before k_gpart writes partials).
    float* lossbt = (float*)d_ws;
    int*   valid  = (int*)(lossbt + 128);
    float* shreg  = (float*)d_ws + 256;
    float* q      = shreg;                                 // B*S*64
    float* kT     = q + (size_t)BB * SS * DMODEL;          // B*64*S
    float* part   = shreg;                                 // 80*C*1088 (aliased)

    // pick C (chunks per batch) to fit ws: 32 -> 16 -> 8
    size_t avail_f = (ws_size > 1024) ? (ws_size / 4 - 256) : 0;
    int C = 32;
    while (C > 8 && (size_t)(BB * NT) * C * 1088 > avail_f) C >>= 1;
    int CS = SS / C;

    hipLaunchKernelGGL(k_mlp, dim3(BB * SS / 4), dim3(256), 0, stream,
                       fps, W1, b1, gamma, beta, W2, b2, Wq, bq, Wk, bk,
                       e_out, q, kT);
    hipLaunchKernelGGL(k_attn, dim3(BB * (SS / 4)), dim3(256), 0, stream,
                       q, kT, alpha);
    hipLaunchKernelGGL(k_gpart, dim3(BB * C), dim3(256), 0, stream,
                       x, y, steps, alpha, part, C, CS);
    hipLaunchKernelGGL(k_solve2, dim3(BB * NT), dim3(256), 0, stream,
                       x, y, steps, alpha, part, lossbt, valid, C);
    hipLaunchKernelGGL(k_final, dim3(1), dim3(128), 0, stream, lossbt, valid, out);
}

// Round 7
// 213.784 us; speedup vs baseline: 3.0859x; 1.1552x over previous
//
#include <hip/hip_runtime.h>
#include <hip/hip_bf16.h>
#include <math.h>

#define BB 16
#define SS 512
#define INDIM 64
#define DMODEL 64
#define HID 256
#define FILT 32
#define TYY 256
#define TXX 287
#define NT 5
#define RIDGEF 0.01f
#define THRESHF 0.005f

// ---------------------------------------------------------------------------
// Kernel 1: fused MLP -> layernorm -> tanh -> W2 -> tanh (e_orig, f32 out)
//           -> +pos-enc -> q, kT.  4 rows per block.  (unchanged, verified)
// ---------------------------------------------------------------------------
__global__ __launch_bounds__(256) void k_mlp(
    const float* __restrict__ fps, const float* __restrict__ W1, const float* __restrict__ b1,
    const float* __restrict__ gamma, const float* __restrict__ beta,
    const float* __restrict__ W2, const float* __restrict__ b2,
    const float* __restrict__ Wq, const float* __restrict__ bq,
    const float* __restrict__ Wk, const float* __restrict__ bk,
    float* __restrict__ e_out, float* __restrict__ q_out, float* __restrict__ kT_out)
{
    const int row0 = blockIdx.x << 2;
    const int tid = threadIdx.x;

    __shared__ float fr[4][INDIM];
    __shared__ float red[4][256];
    __shared__ float th4[4][HID];
    __shared__ float ee4[4][DMODEL];
    __shared__ float part4[4][4][DMODEL];
    __shared__ float partk4[4][4][DMODEL];

    { int r = tid >> 6, i = tid & 63;
      fr[r][i] = fps[(row0 + r) * INDIM + i]; }
    __syncthreads();

    float h[4];
    float b1v = b1[tid];
    #pragma unroll
    for (int r = 0; r < 4; ++r) h[r] = b1v;
    for (int i = 0; i < INDIM; ++i) {
        float w = W1[i * HID + tid];
        #pragma unroll
        for (int r = 0; r < 4; ++r) h[r] = fmaf(fr[r][i], w, h[r]);
    }

    #pragma unroll
    for (int r = 0; r < 4; ++r) red[r][tid] = h[r];
    __syncthreads();
    for (int off = 128; off > 0; off >>= 1) {
        if (tid < off) {
            #pragma unroll
            for (int r = 0; r < 4; ++r) red[r][tid] += red[r][tid + off];
        }
        __syncthreads();
    }
    float mu[4];
    #pragma unroll
    for (int r = 0; r < 4; ++r) mu[r] = red[r][0] * (1.0f / HID);
    __syncthreads();
    #pragma unroll
    for (int r = 0; r < 4; ++r) { float d = h[r] - mu[r]; red[r][tid] = d * d; }
    __syncthreads();
    for (int off = 128; off > 0; off >>= 1) {
        if (tid < off) {
            #pragma unroll
            for (int r = 0; r < 4; ++r) red[r][tid] += red[r][tid + off];
        }
        __syncthreads();
    }
    float gm = gamma[tid], bt = beta[tid];
    #pragma unroll
    for (int r = 0; r < 4; ++r) {
        float var = red[r][0] * (1.0f / HID);
        float hn = (h[r] - mu[r]) * rsqrtf(var + 1e-5f) * gm + bt;
        th4[r][tid] = tanhf(hn);
    }
    __syncthreads();

    { int p = tid >> 6, j = tid & 63;
      float acc[4] = {0.f, 0.f, 0.f, 0.f};
      for (int i = p * 64; i < p * 64 + 64; ++i) {
          float w = W2[i * DMODEL + j];
          #pragma unroll
          for (int r = 0; r < 4; ++r) acc[r] = fmaf(th4[r][i], w, acc[r]);
      }
      #pragma unroll
      for (int r = 0; r < 4; ++r) part4[p][r][j] = acc[r];
    }
    __syncthreads();
    { int r = tid >> 6, j = tid & 63;
      float e = part4[0][r][j] + part4[1][r][j] + part4[2][r][j] + part4[3][r][j] + b2[j];
      float eo = tanhf(e);
      int row = row0 + r;
      int s = row & (SS - 1);
      e_out[(size_t)row * DMODEL + j] = eo;
      float div = expf(-(float)(j & ~1) * 0.14391156831212787f);  // ln(10000)/64
      float ang = (float)s * div;
      float pe = (j & 1) ? cosf(ang) : sinf(ang);
      ee4[r][j] = eo + 0.05f * pe;
    }
    __syncthreads();
    { int p = tid >> 6, j = tid & 63;
      float aq[4] = {0.f,0.f,0.f,0.f}, ak[4] = {0.f,0.f,0.f,0.f};
      for (int i = p * 16; i < p * 16 + 16; ++i) {
          float wqv = Wq[i * DMODEL + j];
          float wkv = Wk[i * DMODEL + j];
          #pragma unroll
          for (int r = 0; r < 4; ++r) {
              aq[r] = fmaf(ee4[r][i], wqv, aq[r]);
              ak[r] = fmaf(ee4[r][i], wkv, ak[r]);
          }
      }
      #pragma unroll
      for (int r = 0; r < 4; ++r) { part4[p][r][j] = aq[r]; partk4[p][r][j] = ak[r]; }
    }
    __syncthreads();
    { int r = tid >> 6, j = tid & 63;
      float qv = part4[0][r][j] + part4[1][r][j] + part4[2][r][j] + part4[3][r][j] + bq[j];
      float kv = partk4[0][r][j] + partk4[1][r][j] + partk4[2][r][j] + partk4[3][r][j] + bk[j];
      int row = row0 + r;
      int b = row >> 9, s = row & (SS - 1);
      q_out[(size_t)row * DMODEL + j] = qv;
      kT_out[(size_t)(b * DMODEL + j) * SS + s] = kv;
    }
}

// ---------------------------------------------------------------------------
// Kernel 2: causal scores + softmax -> alpha f32 into d_out.  (unchanged)
// ---------------------------------------------------------------------------
__global__ __launch_bounds__(256) void k_attn(
    const float* __restrict__ q, const float* __restrict__ kT,
    float* __restrict__ alpha)
{
    const int blk = blockIdx.x;
    const int b = blk >> 7;
    const int t0 = (blk & 127) << 2;
    const int t3 = t0 + 3;
    const int tid = threadIdx.x;
    const int wave = tid >> 6, lane = tid & 63;

    __shared__ float qt[4 * DMODEL];
    __shared__ float redm[4][4];

    qt[tid] = q[(size_t)(b * SS + t0 + (tid >> 6)) * DMODEL + (tid & 63)];
    __syncthreads();

    const float* kTb = kT + (size_t)b * DMODEL * SS;
    const int s0 = tid, s1 = tid + 256;
    float a0[4] = {0,0,0,0}, a1[4] = {0,0,0,0};
    if (s1 <= t3) {
        for (int d = 0; d < DMODEL; ++d) {
            float k0 = kTb[d * SS + s0];
            float k1 = kTb[d * SS + s1];
            #pragma unroll
            for (int r = 0; r < 4; ++r) {
                float qv = qt[r * DMODEL + d];
                a0[r] = fmaf(qv, k0, a0[r]);
                a1[r] = fmaf(qv, k1, a1[r]);
            }
        }
    } else if (s0 <= t3) {
        for (int d = 0; d < DMODEL; ++d) {
            float k0 = kTb[d * SS + s0];
            #pragma unroll
            for (int r = 0; r < 4; ++r) a0[r] = fmaf(qt[r * DMODEL + d], k0, a0[r]);
        }
    }
    float lg0[4], lg1[4];
    #pragma unroll
    for (int r = 0; r < 4; ++r) {
        int tr = t0 + r;
        lg0[r] = (s0 <= tr) ? 0.25f * a0[r] : -INFINITY;
        lg1[r] = (s1 <= tr) ? 0.25f * a1[r] : -INFINITY;
    }
    float mr[4];
    #pragma unroll
    for (int r = 0; r < 4; ++r) {
        float m = fmaxf(lg0[r], lg1[r]);
        #pragma unroll
        for (int off = 32; off > 0; off >>= 1) m = fmaxf(m, __shfl_xor(m, off));
        if (lane == 0) redm[r][wave] = m;
    }
    __syncthreads();
    #pragma unroll
    for (int r = 0; r < 4; ++r)
        mr[r] = fmaxf(fmaxf(redm[r][0], redm[r][1]), fmaxf(redm[r][2], redm[r][3]));
    __syncthreads();
    float ex0[4], ex1[4], sr[4];
    #pragma unroll
    for (int r = 0; r < 4; ++r) {
        ex0[r] = expf(lg0[r] - mr[r]);
        ex1[r] = expf(lg1[r] - mr[r]);
        float sm = ex0[r] + ex1[r];
        #pragma unroll
        for (int off = 32; off > 0; off >>= 1) sm += __shfl_xor(sm, off);
        if (lane == 0) redm[r][wave] = sm;
    }
    __syncthreads();
    #pragma unroll
    for (int r = 0; r < 4; ++r)
        sr[r] = redm[r][0] + redm[r][1] + redm[r][2] + redm[r][3];
    #pragma unroll
    for (int r = 0; r < 4; ++r) {
        float inv = 1.0f / sr[r];
        size_t base = (size_t)(b * SS + t0 + r) * SS;
        alpha[base + s0] = ex0[r] * inv;
        alpha[base + s1] = ex1[r] * inv;
    }
}

// ---------------------------------------------------------------------------
// Kernel 3 (stage 1): per (b, s-chunk).  G_s diagonals built fully in
// parallel: delta-products + 5-step shuffle prefix scan (no serial leg).
// Per-t accumulators in REGISTERS (acc[5][5]); 3 barriers/iter.
// ---------------------------------------------------------------------------
__global__ __launch_bounds__(256) void k_gpart(
    const float* __restrict__ x, const float* __restrict__ y,
    const int* __restrict__ steps, const float* __restrict__ alpha,
    float* __restrict__ part, int C, int CS)
{
    const int b = blockIdx.x / C;
    const int chunk = blockIdx.x % C;
    const int tid = threadIdx.x;
    const int lane = tid & 63, wid = tid >> 6;

    __shared__ float xs[288];
    __shared__ float ys[256];
    __shared__ float Gs[1056];        // 32x33 (pitch 33)
    __shared__ float crossL[32];
    __shared__ float wv[NT * 64];     // CS <= 64
    __shared__ int sl[64];
    __shared__ int nselS;
    __shared__ int stS[NT];
    __shared__ float redA[4][33];
    __shared__ float redB[4][33];

    if (tid < NT) stS[tid] = steps[tid];
    if (tid < 32) Gs[tid * 33 + 32] = 0.f;   // pad column deterministic
    __syncthreads();

    for (int idx = tid; idx < NT * CS; idx += 256) {
        int t = idx / CS, si = idx % CS;
        float a = alpha[(size_t)(b * SS + stS[t]) * SS + chunk * CS + si];
        wv[t * 64 + si] = (a > THRESHF) ? a : 0.f;
    }
    __syncthreads();
    if (tid == 0) {
        int c = 0;
        for (int si = 0; si < CS; ++si) {
            float m = wv[si] + wv[64 + si] + wv[128 + si] + wv[192 + si] + wv[256 + si];
            if (m > 0.f) sl[c++] = si;
        }
        nselS = c;
    }
    __syncthreads();
    const int nsel = nselS;

    // register accumulators: idx = tid + 256*r; r=4 valid only for tid<64
    float acc[NT][5];
    #pragma unroll
    for (int t = 0; t < NT; ++t) {
        #pragma unroll
        for (int r = 0; r < 5; ++r) acc[t][r] = 0.f;
    }

    float rx0 = 0.f, rx1 = 0.f, ry = 0.f;
    if (nsel > 0) {
        int sg = chunk * CS + sl[0];
        const float* xr = x + (size_t)(b * SS + sg) * TXX;
        const float* yr = y + (size_t)(b * SS + sg) * TYY;
        rx0 = xr[tid];
        if (tid < 31) rx1 = xr[256 + tid];
        ry = yr[tid];
    }

    for (int i = 0; i < nsel; ++i) {
        xs[tid] = rx0;
        if (tid < 31) xs[256 + tid] = rx1;
        ys[tid] = ry;
        const int sl_cur = sl[i];
        __syncthreads();                      // (a) staged; all waves past acc

        if (i + 1 < nsel) {                   // prefetch next selected row
            int sg = chunk * CS + sl[i + 1];
            const float* xr = x + (size_t)(b * SS + sg) * TXX;
            const float* yr = y + (size_t)(b * SS + sg) * TYY;
            rx0 = xr[tid];
            if (tid < 31) rx1 = xr[256 + tid];
            ry = yr[tid];
        }

        // dot partials: C[l] and G0[d=l]
        { int l = tid & 31, p = tid >> 5;
          float c = 0.f, a = 0.f;
          const int k0 = p * 32;
          #pragma unroll
          for (int kk = 0; kk < 32; ++kk) {
              int k = k0 + kk;
              float xv = xs[k + l];
              c = fmaf(xv, ys[k], c);
              a = fmaf(xs[k], xv, a);
          }
          c += __shfl_xor(c, 32);
          a += __shfl_xor(a, 32);
          if (lane < 32) { redA[wid][l] = c; redB[wid][l] = a; }
        }
        __syncthreads();                      // (b) partials ready

        if (tid < 32)
            crossL[tid] = redA[0][tid] + redA[1][tid] + redA[2][tid] + redA[3][tid];

        // parallel diagonals: 4 passes x (2 diagonals per wave)
        { int jj = lane & 31;
          #pragma unroll
          for (int pass = 0; pass < 4; ++pass) {
              int dd = 2 * (wid + 4 * pass) + (lane >> 5);
              float g0 = redB[0][dd] + redB[1][dd] + redB[2][dd] + redB[3][dd];
              float dlt = 0.f;
              if (jj > 0 && jj + dd < 32)
                  dlt = xs[jj + 255] * xs[jj + 255 + dd]
                      - xs[jj - 1] * xs[jj - 1 + dd];
              #pragma unroll
              for (int off = 1; off < 32; off <<= 1) {
                  float tsh = __shfl_up(dlt, off, 32);
                  if (jj >= off) dlt += tsh;
              }
              if (jj + dd < 32) {
                  float gval = g0 + dlt;
                  Gs[jj * 33 + jj + dd] = gval;
                  Gs[(jj + dd) * 33 + jj] = gval;
              }
          }
        }
        __syncthreads();                      // (c) Gs/crossL ready

        #pragma unroll
        for (int t = 0; t < NT; ++t) {
            float w = wv[t * 64 + sl_cur];
            if (w > 0.f) {
                #pragma unroll
                for (int r = 0; r < 4; ++r)
                    acc[t][r] = fmaf(w, Gs[tid + 256 * r], acc[t][r]);
                if (tid < 32)      acc[t][4] = fmaf(w, Gs[1024 + tid], acc[t][4]);
                else if (tid < 64) acc[t][4] = fmaf(w, crossL[tid - 32], acc[t][4]);
            }
        }
        // no barrier: next-iter (a) protects xs; acc readers don't touch xs
    }

    #pragma unroll
    for (int t = 0; t < NT; ++t) {
        size_t base = (size_t)((b * NT + t) * C + chunk) * 1088;
        #pragma unroll
        for (int r = 0; r < 4; ++r) part[base + tid + 256 * r] = acc[t][r];
        if (tid < 64) part[base + 1024 + tid] = acc[t][4];
    }
}

// ---------------------------------------------------------------------------
// Kernel 4 (stage 2): per (b,t): sum chunk partials, +ridge, Cholesky
// (2 barriers/k), wave-synchronous shuffle triangular solves (0 barriers),
// prediction loss, valid flag.
// ---------------------------------------------------------------------------
__global__ __launch_bounds__(256) void k_solve2(
    const float* __restrict__ x, const float* __restrict__ y,
    const int* __restrict__ steps, const float* __restrict__ alpha,
    const float* __restrict__ part,
    float* __restrict__ lossbt, int* __restrict__ valid, int C)
{
    const int g = blockIdx.x;
    const int b = g / NT, t = g % NT;
    const int tid = threadIdx.x;

    __shared__ float Af[1056];   // pitch 33
    __shared__ float zs[FILT];
    __shared__ float wt[FILT];
    __shared__ float xsr[TXX + 1];
    __shared__ float red[256];
    __shared__ int step_s;
    __shared__ int anyv;

    if (tid == 0) { step_s = steps[t]; anyv = 0; }
    __syncthreads();

    float a0 = 0.f, a1 = 0.f, a2 = 0.f, a3 = 0.f, a4 = 0.f;
    for (int ch = 0; ch < C; ++ch) {
        const float* pp = part + (size_t)(g * C + ch) * 1088;
        a0 += pp[tid];
        a1 += pp[tid + 256];
        a2 += pp[tid + 512];
        a3 += pp[tid + 768];
        if (tid < 64) a4 += pp[tid + 1024];
    }
    Af[tid] = a0; Af[tid + 256] = a1; Af[tid + 512] = a2; Af[tid + 768] = a3;
    if (tid < 32) Af[1024 + tid] = a4;
    else if (tid < 64) zs[tid - 32] = a4;

    { const float* arow = alpha + (size_t)(b * SS + step_s) * SS;
      if (arow[tid] > THRESHF || arow[tid + 256] > THRESHF) anyv = 1; }
    __syncthreads();
    if (tid < 32) Af[tid * 33 + tid] += RIDGEF;
    __syncthreads();

    // Cholesky (lower), 2 barriers per k.  Column normalize is
    // wave-synchronous: all lanes (tid<32, one wave) read A[k][k] in the same
    // instruction before lane k overwrites it.
    for (int k = 0; k < FILT; ++k) {
        if (tid < FILT && tid >= k) {
            float dk = sqrtf(Af[k * 33 + k]);
            if (tid == k) Af[k * 33 + k] = dk;
            else          Af[tid * 33 + k] = Af[tid * 33 + k] / dk;
        }
        __syncthreads();
        #pragma unroll
        for (int r = 0; r < 4; ++r) {
            int idx = tid + 256 * r, i = idx >> 5, j = idx & 31;
            if (i > k && j > k && j <= i)
                Af[i * 33 + j] -= Af[i * 33 + k] * Af[j * 33 + k];
        }
        __syncthreads();
    }

    // Triangular solves: wave 0 only, z in registers, Af read-only -> no
    // barriers, no LDS ordering hazards.  Lanes 32-63 run a redundant copy.
    if (tid < 64) {
        int l = tid & 31;
        float zl = zs[l];
        for (int k = 0; k < FILT; ++k) {         // forward: L z' = z
            float lkk = Af[k * 33 + k];
            float zk = __shfl(zl, k, 64) / lkk;
            if (l == k) zl = zk;
            else if (l > k) zl = fmaf(-Af[l * 33 + k], zk, zl);
        }
        for (int k = FILT - 1; k >= 0; --k) {    // backward: L^T w = z'
            float lkk = Af[k * 33 + k];
            float zk = __shfl(zl, k, 64) / lkk;
            if (l == k) zl = zk;
            else if (l < k) zl = fmaf(-Af[k * 33 + l], zk, zl);
        }
        if (tid < 32) wt[l] = zl;
    }
    __syncthreads();

    // pred + per-(b,t) loss
    const int sstep = step_s;
    const float* xrow = x + (size_t)(b * SS + sstep) * TXX;
    for (int i = tid; i < TXX; i += 256) xsr[i] = xrow[i];
    __syncthreads();
    float pk = 0.f;
    #pragma unroll
    for (int l = 0; l < FILT; ++l) pk = fmaf(xsr[tid + l], wt[l], pk);
    float d = y[(size_t)(b * SS + sstep) * TYY + tid] - pk;
    red[tid] = d * d;
    __syncthreads();
    for (int off = 128; off > 0; off >>= 1) {
        if (tid < off) red[tid] += red[tid + off];
        __syncthreads();
    }
    if (tid == 0) {
        lossbt[g] = red[0] * (1.0f / TYY);
        valid[g] = anyv;
    }
}

// ---------------------------------------------------------------------------
// Kernel 5: final masked mean -> out[0] (f32)
// ---------------------------------------------------------------------------
__global__ __launch_bounds__(128) void k_final(
    const float* __restrict__ lossbt, const int* __restrict__ valid,
    float* __restrict__ out0)
{
    __shared__ float rs[128];
    __shared__ int rc[128];
    int tid = threadIdx.x;
    float v = 0.f; int c = 0;
    if (tid < BB * NT && valid[tid]) { v = lossbt[tid]; c = 1; }
    rs[tid] = v; rc[tid] = c;
    __syncthreads();
    for (int off = 64; off > 0; off >>= 1) {
        if (tid < off) { rs[tid] += rs[tid + off]; rc[tid] += rc[tid + off]; }
        __syncthreads();
    }
    if (tid == 0) {
        int n = rc[0] > 0 ? rc[0] : 1;
        out0[0] = rs[0] / (float)n;
    }
}

extern "C" void kernel_launch(void* const* d_in, const int* in_sizes, int n_in,
                              void* d_out, int out_size, void* d_ws, size_t ws_size,
                              hipStream_t stream)
{
    const float* fps  = (const float*)d_in[0];
    const float* x    = (const float*)d_in[1];
    const float* y    = (const float*)d_in[2];
    const int* steps  = (const int*)d_in[3];
    const float* W1   = (const float*)d_in[4];
    const float* b1   = (const float*)d_in[5];
    const float* gamma= (const float*)d_in[6];
    const float* beta = (const float*)d_in[7];
    const float* W2   = (const float*)d_in[8];
    const float* b2   = (const float*)d_in[9];
    const float* Wq   = (const float*)d_in[10];
    const float* bq   = (const float*)d_in[11];
    const float* Wk   = (const float*)d_in[12];
    const float* bk   = (const float*)d_in[13];

    // Output f32 flat: [loss(1) | alpha(B*S*S) | e_orig(B*S*D)]
    float* out   = (float*)d_out;
    float* alpha = out + 1;
    float* e_out = out + 1 + (size_t)BB * SS * SS;

    // ws: [lossbt(128) | valid(128 ints) | shared region]
    // shared region: q+kT during mlp/attn; chunk partials afterwards (aliased —
    // stream order guarantees q/kT dead before k_gpart writes partials).
    float* lossbt = (float*)d_ws;
    int*   valid  = (int*)(lossbt + 128);
    float* shreg  = (float*)d_ws + 256;
    float* q      = shreg;                                 // B*S*64
    float* kT     = q + (size_t)BB * SS * DMODEL;          // B*64*S
    float* part   = shreg;                                 // 80*C*1088 (aliased)

    size_t avail_f = (ws_size > 1024) ? (ws_size / 4 - 256) : 0;
    int C = 32;
    while (C > 8 && (size_t)(BB * NT) * C * 1088 > avail_f) C >>= 1;
    int CS = SS / C;

    hipLaunchKernelGGL(k_mlp, dim3(BB * SS / 4), dim3(256), 0, stream,
                       fps, W1, b1, gamma, beta, W2, b2, Wq, bq, Wk, bk,
                       e_out, q, kT);
    hipLaunchKernelGGL(k_attn, dim3(BB * (SS / 4)), dim3(256), 0, stream,
                       q, kT, alpha);
    hipLaunchKernelGGL(k_gpart, dim3(BB * C), dim3(256), 0, stream,
                       x, y, steps, alpha, part, C, CS);
    hipLaunchKernelGGL(k_solve2, dim3(BB * NT), dim3(256), 0, stream,
                       x, y, steps, alpha, part, lossbt, valid, C);
    hipLaunchKernelGGL(k_final, dim3(1), dim3(128), 0, stream, lossbt, valid, out);
}

// Round 8
// 209.868 us; speedup vs baseline: 3.1435x; 1.0187x over previous
//
#include <hip/hip_runtime.h>
#include <hip/hip_bf16.h>
#include <math.h>

#define BB 16
#define SS 512
#define INDIM 64
#define DMODEL 64
#define HID 256
#define FILT 32
#define TYY 256
#define TXX 287
#define NT 5
#define RIDGEF 0.01f
#define THRESHF 0.005f

// ---------------------------------------------------------------------------
// Kernel 1: fused MLP -> layernorm -> tanh -> W2 -> tanh (e_orig) -> +pos-enc
//           -> q, kT.  Mean/var via ONE fused shuffle reduction (2 barriers
//           in that section instead of 16).
// ---------------------------------------------------------------------------
__global__ __launch_bounds__(256) void k_mlp(
    const float* __restrict__ fps, const float* __restrict__ W1, const float* __restrict__ b1,
    const float* __restrict__ gamma, const float* __restrict__ beta,
    const float* __restrict__ W2, const float* __restrict__ b2,
    const float* __restrict__ Wq, const float* __restrict__ bq,
    const float* __restrict__ Wk, const float* __restrict__ bk,
    float* __restrict__ e_out, float* __restrict__ q_out, float* __restrict__ kT_out)
{
    const int row0 = blockIdx.x << 2;
    const int tid = threadIdx.x;
    const int wid = tid >> 6, lane = tid & 63;

    __shared__ float fr[4][INDIM];
    __shared__ float th4[4][HID];
    __shared__ float ee4[4][DMODEL];
    __shared__ float part4[4][4][DMODEL];
    __shared__ float partk4[4][4][DMODEL];
    __shared__ float wred[4][4][2];

    { int r = tid >> 6, i = tid & 63;
      fr[r][i] = fps[(row0 + r) * INDIM + i]; }
    __syncthreads();

    float h[4];
    float b1v = b1[tid];
    #pragma unroll
    for (int r = 0; r < 4; ++r) h[r] = b1v;
    for (int i = 0; i < INDIM; ++i) {
        float w = W1[i * HID + tid];
        #pragma unroll
        for (int r = 0; r < 4; ++r) h[r] = fmaf(fr[r][i], w, h[r]);
    }

    // fused sum / sum-of-squares reduction (wave shuffle + cross-wave LDS)
    float s1[4], s2[4];
    #pragma unroll
    for (int r = 0; r < 4; ++r) { s1[r] = h[r]; s2[r] = h[r] * h[r]; }
    #pragma unroll
    for (int off = 1; off < 64; off <<= 1) {
        #pragma unroll
        for (int r = 0; r < 4; ++r) {
            s1[r] += __shfl_xor(s1[r], off);
            s2[r] += __shfl_xor(s2[r], off);
        }
    }
    if (lane == 0) {
        #pragma unroll
        for (int r = 0; r < 4; ++r) { wred[wid][r][0] = s1[r]; wred[wid][r][1] = s2[r]; }
    }
    __syncthreads();
    float gm = gamma[tid], bt = beta[tid];
    #pragma unroll
    for (int r = 0; r < 4; ++r) {
        float t1 = wred[0][r][0] + wred[1][r][0] + wred[2][r][0] + wred[3][r][0];
        float t2 = wred[0][r][1] + wred[1][r][1] + wred[2][r][1] + wred[3][r][1];
        float mu = t1 * (1.0f / HID);
        float var = t2 * (1.0f / HID) - mu * mu;
        float hn = (h[r] - mu) * rsqrtf(var + 1e-5f) * gm + bt;
        th4[r][tid] = tanhf(hn);
    }
    __syncthreads();

    { int p = tid >> 6, j = tid & 63;
      float acc[4] = {0.f, 0.f, 0.f, 0.f};
      for (int i = p * 64; i < p * 64 + 64; ++i) {
          float w = W2[i * DMODEL + j];
          #pragma unroll
          for (int r = 0; r < 4; ++r) acc[r] = fmaf(th4[r][i], w, acc[r]);
      }
      #pragma unroll
      for (int r = 0; r < 4; ++r) part4[p][r][j] = acc[r];
    }
    __syncthreads();
    { int r = tid >> 6, j = tid & 63;
      float e = part4[0][r][j] + part4[1][r][j] + part4[2][r][j] + part4[3][r][j] + b2[j];
      float eo = tanhf(e);
      int row = row0 + r;
      int s = row & (SS - 1);
      e_out[(size_t)row * DMODEL + j] = eo;
      float div = expf(-(float)(j & ~1) * 0.14391156831212787f);  // ln(10000)/64
      float ang = (float)s * div;
      float pe = (j & 1) ? cosf(ang) : sinf(ang);
      ee4[r][j] = eo + 0.05f * pe;
    }
    __syncthreads();
    { int p = tid >> 6, j = tid & 63;
      float aq[4] = {0.f,0.f,0.f,0.f}, ak[4] = {0.f,0.f,0.f,0.f};
      for (int i = p * 16; i < p * 16 + 16; ++i) {
          float wqv = Wq[i * DMODEL + j];
          float wkv = Wk[i * DMODEL + j];
          #pragma unroll
          for (int r = 0; r < 4; ++r) {
              aq[r] = fmaf(ee4[r][i], wqv, aq[r]);
              ak[r] = fmaf(ee4[r][i], wkv, ak[r]);
          }
      }
      #pragma unroll
      for (int r = 0; r < 4; ++r) { part4[p][r][j] = aq[r]; partk4[p][r][j] = ak[r]; }
    }
    __syncthreads();
    { int r = tid >> 6, j = tid & 63;
      float qv = part4[0][r][j] + part4[1][r][j] + part4[2][r][j] + part4[3][r][j] + bq[j];
      float kv = partk4[0][r][j] + partk4[1][r][j] + partk4[2][r][j] + partk4[3][r][j] + bk[j];
      int row = row0 + r;
      int b = row >> 9, s = row & (SS - 1);
      q_out[(size_t)row * DMODEL + j] = qv;
      kT_out[(size_t)(b * DMODEL + j) * SS + s] = kv;
    }
}

// ---------------------------------------------------------------------------
// Kernel 2: causal scores + softmax -> alpha f32 into d_out.  (unchanged)
// ---------------------------------------------------------------------------
__global__ __launch_bounds__(256) void k_attn(
    const float* __restrict__ q, const float* __restrict__ kT,
    float* __restrict__ alpha)
{
    const int blk = blockIdx.x;
    const int b = blk >> 7;
    const int t0 = (blk & 127) << 2;
    const int t3 = t0 + 3;
    const int tid = threadIdx.x;
    const int wave = tid >> 6, lane = tid & 63;

    __shared__ float qt[4 * DMODEL];
    __shared__ float redm[4][4];

    qt[tid] = q[(size_t)(b * SS + t0 + (tid >> 6)) * DMODEL + (tid & 63)];
    __syncthreads();

    const float* kTb = kT + (size_t)b * DMODEL * SS;
    const int s0 = tid, s1 = tid + 256;
    float a0[4] = {0,0,0,0}, a1[4] = {0,0,0,0};
    if (s1 <= t3) {
        for (int d = 0; d < DMODEL; ++d) {
            float k0 = kTb[d * SS + s0];
            float k1 = kTb[d * SS + s1];
            #pragma unroll
            for (int r = 0; r < 4; ++r) {
                float qv = qt[r * DMODEL + d];
                a0[r] = fmaf(qv, k0, a0[r]);
                a1[r] = fmaf(qv, k1, a1[r]);
            }
        }
    } else if (s0 <= t3) {
        for (int d = 0; d < DMODEL; ++d) {
            float k0 = kTb[d * SS + s0];
            #pragma unroll
            for (int r = 0; r < 4; ++r) a0[r] = fmaf(qt[r * DMODEL + d], k0, a0[r]);
        }
    }
    float lg0[4], lg1[4];
    #pragma unroll
    for (int r = 0; r < 4; ++r) {
        int tr = t0 + r;
        lg0[r] = (s0 <= tr) ? 0.25f * a0[r] : -INFINITY;
        lg1[r] = (s1 <= tr) ? 0.25f * a1[r] : -INFINITY;
    }
    float mr[4];
    #pragma unroll
    for (int r = 0; r < 4; ++r) {
        float m = fmaxf(lg0[r], lg1[r]);
        #pragma unroll
        for (int off = 32; off > 0; off >>= 1) m = fmaxf(m, __shfl_xor(m, off));
        if (lane == 0) redm[r][wave] = m;
    }
    __syncthreads();
    #pragma unroll
    for (int r = 0; r < 4; ++r)
        mr[r] = fmaxf(fmaxf(redm[r][0], redm[r][1]), fmaxf(redm[r][2], redm[r][3]));
    __syncthreads();
    float ex0[4], ex1[4], sr[4];
    #pragma unroll
    for (int r = 0; r < 4; ++r) {
        ex0[r] = expf(lg0[r] - mr[r]);
        ex1[r] = expf(lg1[r] - mr[r]);
        float sm = ex0[r] + ex1[r];
        #pragma unroll
        for (int off = 32; off > 0; off >>= 1) sm += __shfl_xor(sm, off);
        if (lane == 0) redm[r][wave] = sm;
    }
    __syncthreads();
    #pragma unroll
    for (int r = 0; r < 4; ++r)
        sr[r] = redm[r][0] + redm[r][1] + redm[r][2] + redm[r][3];
    #pragma unroll
    for (int r = 0; r < 4; ++r) {
        float inv = 1.0f / sr[r];
        size_t base = (size_t)(b * SS + t0 + r) * SS;
        alpha[base + s0] = ex0[r] * inv;
        alpha[base + s1] = ex1[r] * inv;
    }
}

// ---------------------------------------------------------------------------
// Kernel 3 (stage 1): per (b, s-chunk).  float4 broadcast reads in the dot
// loops (ds_read_b128), parallel prefix-scan diagonals, register acc.
// ---------------------------------------------------------------------------
__global__ __launch_bounds__(256) void k_gpart(
    const float* __restrict__ x, const float* __restrict__ y,
    const int* __restrict__ steps, const float* __restrict__ alpha,
    float* __restrict__ part, int C, int CS)
{
    const int b = blockIdx.x / C;
    const int chunk = blockIdx.x % C;
    const int tid = threadIdx.x;
    const int lane = tid & 63, wid = tid >> 6;

    __shared__ __align__(16) float xs[288];
    __shared__ __align__(16) float ys[256];
    __shared__ float Gs[1056];        // 32x33 (pitch 33)
    __shared__ float crossL[32];
    __shared__ float wv[NT * 64];
    __shared__ int sl[64];
    __shared__ int nselS;
    __shared__ int stS[NT];
    __shared__ float redA[4][33];
    __shared__ float redB[4][33];

    if (tid < NT) stS[tid] = steps[tid];
    if (tid < 32) Gs[tid * 33 + 32] = 0.f;   // pad column deterministic
    __syncthreads();

    for (int idx = tid; idx < NT * CS; idx += 256) {
        int t = idx / CS, si = idx % CS;
        float a = alpha[(size_t)(b * SS + stS[t]) * SS + chunk * CS + si];
        wv[t * 64 + si] = (a > THRESHF) ? a : 0.f;
    }
    __syncthreads();
    if (tid == 0) {
        int c = 0;
        for (int si = 0; si < CS; ++si) {
            float m = wv[si] + wv[64 + si] + wv[128 + si] + wv[192 + si] + wv[256 + si];
            if (m > 0.f) sl[c++] = si;
        }
        nselS = c;
    }
    __syncthreads();
    const int nsel = nselS;

    float acc[NT][5];
    #pragma unroll
    for (int t = 0; t < NT; ++t) {
        #pragma unroll
        for (int r = 0; r < 5; ++r) acc[t][r] = 0.f;
    }

    float rx0 = 0.f, rx1 = 0.f, ry = 0.f;
    if (nsel > 0) {
        int sg = chunk * CS + sl[0];
        const float* xr = x + (size_t)(b * SS + sg) * TXX;
        const float* yr = y + (size_t)(b * SS + sg) * TYY;
        rx0 = xr[tid];
        if (tid < 31) rx1 = xr[256 + tid];
        ry = yr[tid];
    }

    for (int i = 0; i < nsel; ++i) {
        xs[tid] = rx0;
        if (tid < 31) xs[256 + tid] = rx1;
        ys[tid] = ry;
        const int sl_cur = sl[i];
        __syncthreads();                      // (a) staged

        if (i + 1 < nsel) {                   // prefetch next selected row
            int sg = chunk * CS + sl[i + 1];
            const float* xr = x + (size_t)(b * SS + sg) * TXX;
            const float* yr = y + (size_t)(b * SS + sg) * TYY;
            rx0 = xr[tid];
            if (tid < 31) rx1 = xr[256 + tid];
            ry = yr[tid];
        }

        // dot partials: C[l] and G0[d=l], broadcasts via float4 LDS reads
        { int l = tid & 31, p = tid >> 5;
          const float4* xk4 = (const float4*)(xs + (p << 5));
          const float4* yk4 = (const float4*)(ys + (p << 5));
          float c = 0.f, a = 0.f;
          #pragma unroll
          for (int j = 0; j < 8; ++j) {
              float4 xk = xk4[j];
              float4 yk = yk4[j];
              int kb = (p << 5) + (j << 2);
              float x0 = xs[kb + l],     x1 = xs[kb + 1 + l];
              float x2 = xs[kb + 2 + l], x3 = xs[kb + 3 + l];
              c = fmaf(x0, yk.x, c); a = fmaf(xk.x, x0, a);
              c = fmaf(x1, yk.y, c); a = fmaf(xk.y, x1, a);
              c = fmaf(x2, yk.z, c); a = fmaf(xk.z, x2, a);
              c = fmaf(x3, yk.w, c); a = fmaf(xk.w, x3, a);
          }
          c += __shfl_xor(c, 32);
          a += __shfl_xor(a, 32);
          if (lane < 32) { redA[wid][l] = c; redB[wid][l] = a; }
        }
        __syncthreads();                      // (b) partials ready

        if (tid < 32)
            crossL[tid] = redA[0][tid] + redA[1][tid] + redA[2][tid] + redA[3][tid];

        // parallel diagonals: 4 passes x (2 diagonals per wave), prefix scan
        { int jj = lane & 31;
          #pragma unroll
          for (int pass = 0; pass < 4; ++pass) {
              int dd = 2 * (wid + 4 * pass) + (lane >> 5);
              float g0 = redB[0][dd] + redB[1][dd] + redB[2][dd] + redB[3][dd];
              float dlt = 0.f;
              if (jj > 0 && jj + dd < 32)
                  dlt = xs[jj + 255] * xs[jj + 255 + dd]
                      - xs[jj - 1] * xs[jj - 1 + dd];
              #pragma unroll
              for (int off = 1; off < 32; off <<= 1) {
                  float tsh = __shfl_up(dlt, off, 32);
                  if (jj >= off) dlt += tsh;
              }
              if (jj + dd < 32) {
                  float gval = g0 + dlt;
                  Gs[jj * 33 + jj + dd] = gval;
                  Gs[(jj + dd) * 33 + jj] = gval;
              }
          }
        }
        __syncthreads();                      // (c) Gs/crossL ready

        // hoisted Gs reads shared across all 5 sample steps
        { float g0 = Gs[tid], g1 = Gs[tid + 256], g2 = Gs[tid + 512], g3 = Gs[tid + 768];
          float g4 = (tid < 32) ? Gs[1024 + tid]
                   : ((tid < 64) ? crossL[tid - 32] : 0.f);
          #pragma unroll
          for (int t = 0; t < NT; ++t) {
              float w = wv[t * 64 + sl_cur];
              if (w > 0.f) {
                  acc[t][0] = fmaf(w, g0, acc[t][0]);
                  acc[t][1] = fmaf(w, g1, acc[t][1]);
                  acc[t][2] = fmaf(w, g2, acc[t][2]);
                  acc[t][3] = fmaf(w, g3, acc[t][3]);
                  acc[t][4] = fmaf(w, g4, acc[t][4]);
              }
          }
        }
        // no barrier: next-iter (a) protects xs
    }

    #pragma unroll
    for (int t = 0; t < NT; ++t) {
        size_t base = (size_t)((b * NT + t) * C + chunk) * 1088;
        #pragma unroll
        for (int r = 0; r < 4; ++r) part[base + tid + 256 * r] = acc[t][r];
        if (tid < 64) part[base + 1024 + tid] = acc[t][4];
    }
}

// ---------------------------------------------------------------------------
// Kernel 4 (stage 2): per (b,t): sum chunk partials, +ridge, then a fully
// register-resident single-wave Cholesky (lane i owns row i, pivots via
// __shfl, ZERO barriers) + shuffle triangular solves, prediction loss.
// ---------------------------------------------------------------------------
__global__ __launch_bounds__(256) void k_solve2(
    const float* __restrict__ x, const float* __restrict__ y,
    const int* __restrict__ steps, const float* __restrict__ alpha,
    const float* __restrict__ part,
    float* __restrict__ lossbt, int* __restrict__ valid, int C)
{
    const int g = blockIdx.x;
    const int b = g / NT, t = g % NT;
    const int tid = threadIdx.x;

    __shared__ float Af[1056];   // pitch 33
    __shared__ float zs[FILT];
    __shared__ float wt[FILT];
    __shared__ float xsr[TXX + 1];
    __shared__ float red[256];
    __shared__ int step_s;
    __shared__ int anyv;

    if (tid == 0) { step_s = steps[t]; anyv = 0; }
    __syncthreads();

    float a0 = 0.f, a1 = 0.f, a2 = 0.f, a3 = 0.f, a4 = 0.f;
    for (int ch = 0; ch < C; ++ch) {
        const float* pp = part + (size_t)(g * C + ch) * 1088;
        a0 += pp[tid];
        a1 += pp[tid + 256];
        a2 += pp[tid + 512];
        a3 += pp[tid + 768];
        if (tid < 64) a4 += pp[tid + 1024];
    }
    Af[tid] = a0; Af[tid + 256] = a1; Af[tid + 512] = a2; Af[tid + 768] = a3;
    if (tid < 32) Af[1024 + tid] = a4;
    else if (tid < 64) zs[tid - 32] = a4;

    { const float* arow = alpha + (size_t)(b * SS + step_s) * SS;
      if (arow[tid] > THRESHF || arow[tid + 256] > THRESHF) anyv = 1; }
    __syncthreads();
    if (tid < 32) Af[tid * 33 + tid] += RIDGEF;
    __syncthreads();

    // single-wave register Cholesky: lane i holds row i
    if (tid < 32) {
        float a[32];
        #pragma unroll
        for (int j = 0; j < 32; ++j) a[j] = Af[tid * 33 + j];
        #pragma unroll
        for (int k = 0; k < 32; ++k) {
            float akk = __shfl(a[k], k);
            float dk = sqrtf(akk);
            float ck = a[k] / dk;            // lane k gets dk; lanes<k garbage (masked below)
            if (tid >= k) a[k] = ck;
            #pragma unroll
            for (int m = k + 1; m < 32; ++m) {
                float cm = __shfl(ck, m);    // L[m][k]
                if (tid >= m) a[m] = fmaf(-ck, cm, a[m]);
            }
        }
        // write back lower triangle (for transpose access in backward solve)
        #pragma unroll
        for (int j = 0; j < 32; ++j)
            if (j <= tid) Af[tid * 33 + j] = a[j];

        // forward: L z' = z  (registers only)
        float zl = zs[tid];
        #pragma unroll
        for (int k = 0; k < 32; ++k) {
            float akk = __shfl(a[k], k);
            float zk = __shfl(zl, k) / akk;
            if (tid == k) zl = zk;
            else if (tid > k) zl = fmaf(-a[k], zk, zl);
        }
        // backward: L^T w = z'  (transpose rows via LDS write-back)
        #pragma unroll
        for (int k = 31; k >= 0; --k) {
            float akk = __shfl(a[k], k);
            float wk = __shfl(zl, k) / akk;
            if (tid == k) zl = wk;
            else if (tid < k) zl = fmaf(-Af[k * 33 + tid], wk, zl);
        }
        wt[tid] = zl;
    }
    __syncthreads();

    // pred + per-(b,t) loss
    const int sstep = step_s;
    const float* xrow = x + (size_t)(b * SS + sstep) * TXX;
    for (int i = tid; i < TXX; i += 256) xsr[i] = xrow[i];
    __syncthreads();
    float pk = 0.f;
    #pragma unroll
    for (int l = 0; l < FILT; ++l) pk = fmaf(xsr[tid + l], wt[l], pk);
    float d = y[(size_t)(b * SS + sstep) * TYY + tid] - pk;
    red[tid] = d * d;
    __syncthreads();
    for (int off = 128; off > 0; off >>= 1) {
        if (tid < off) red[tid] += red[tid + off];
        __syncthreads();
    }
    if (tid == 0) {
        lossbt[g] = red[0] * (1.0f / TYY);
        valid[g] = anyv;
    }
}

// ---------------------------------------------------------------------------
// Kernel 5: final masked mean -> out[0] (f32)
// ---------------------------------------------------------------------------
__global__ __launch_bounds__(128) void k_final(
    const float* __restrict__ lossbt, const int* __restrict__ valid,
    float* __restrict__ out0)
{
    __shared__ float rs[128];
    __shared__ int rc[128];
    int tid = threadIdx.x;
    float v = 0.f; int c = 0;
    if (tid < BB * NT && valid[tid]) { v = lossbt[tid]; c = 1; }
    rs[tid] = v; rc[tid] = c;
    __syncthreads();
    for (int off = 64; off > 0; off >>= 1) {
        if (tid < off) { rs[tid] += rs[tid + off]; rc[tid] += rc[tid + off]; }
        __syncthreads();
    }
    if (tid == 0) {
        int n = rc[0] > 0 ? rc[0] : 1;
        out0[0] = rs[0] / (float)n;
    }
}

extern "C" void kernel_launch(void* const* d_in, const int* in_sizes, int n_in,
                              void* d_out, int out_size, void* d_ws, size_t ws_size,
                              hipStream_t stream)
{
    const float* fps  = (const float*)d_in[0];
    const float* x    = (const float*)d_in[1];
    const float* y    = (const float*)d_in[2];
    const int* steps  = (const int*)d_in[3];
    const float* W1   = (const float*)d_in[4];
    const float* b1   = (const float*)d_in[5];
    const float* gamma= (const float*)d_in[6];
    const float* beta = (const float*)d_in[7];
    const float* W2   = (const float*)d_in[8];
    const float* b2   = (const float*)d_in[9];
    const float* Wq   = (const float*)d_in[10];
    const float* bq   = (const float*)d_in[11];
    const float* Wk   = (const float*)d_in[12];
    const float* bk   = (const float*)d_in[13];

    // Output f32 flat: [loss(1) | alpha(B*S*S) | e_orig(B*S*D)]
    float* out   = (float*)d_out;
    float* alpha = out + 1;
    float* e_out = out + 1 + (size_t)BB * SS * SS;

    // ws (~256 MiB confirmed by poison fill): small buffers first, then a
    // shared region (q+kT during mlp/attn; chunk partials afterwards, aliased
    // safely by stream order).
    float* lossbt = (float*)d_ws;
    int*   valid  = (int*)(lossbt + 128);
    float* shreg  = (float*)d_ws + 256;
    float* q      = shreg;                                 // B*S*64
    float* kT     = q + (size_t)BB * SS * DMODEL;          // B*64*S
    float* part   = shreg;                                 // 80*C*1088 (aliased)

    size_t avail_f = (ws_size > 1024) ? (ws_size / 4 - 256) : 0;
    int C = 64;
    while (C > 8 && (size_t)(BB * NT) * C * 1088 > avail_f) C >>= 1;
    int CS = SS / C;

    hipLaunchKernelGGL(k_mlp, dim3(BB * SS / 4), dim3(256), 0, stream,
                       fps, W1, b1, gamma, beta, W2, b2, Wq, bq, Wk, bk,
                       e_out, q, kT);
    hipLaunchKernelGGL(k_attn, dim3(BB * (SS / 4)), dim3(256), 0, stream,
                       q, kT, alpha);
    hipLaunchKernelGGL(k_gpart, dim3(BB * C), dim3(256), 0, stream,
                       x, y, steps, alpha, part, C, CS);
    hipLaunchKernelGGL(k_solve2, dim3(BB * NT), dim3(256), 0, stream,
                       x, y, steps, alpha, part, lossbt, valid, C);
    hipLaunchKernelGGL(k_final, dim3(1), dim3(128), 0, stream, lossbt, valid, out);
}

// Round 9
// 208.632 us; speedup vs baseline: 3.1622x; 1.0059x over previous
//
#include <hip/hip_runtime.h>
#include <hip/hip_bf16.h>
#include <math.h>

#define BB 16
#define SS 512
#define INDIM 64
#define DMODEL 64
#define HID 256
#define FILT 32
#define TYY 256
#define TXX 287
#define NT 5
#define RIDGEF 0.01f
#define THRESHF 0.005f

// ---------------------------------------------------------------------------
// Kernel 1: fused MLP -> LN -> tanh -> W2 -> tanh (e_orig) -> +pos-enc -> q,kT.
// 8 rows per block (weight L2 reads amortized 8x); fused shuffle mean/var.
// e/q/k epilogue in two 4-row passes to bound LDS.
// ---------------------------------------------------------------------------
__global__ __launch_bounds__(256) void k_mlp(
    const float* __restrict__ fps, const float* __restrict__ W1, const float* __restrict__ b1,
    const float* __restrict__ gamma, const float* __restrict__ beta,
    const float* __restrict__ W2, const float* __restrict__ b2,
    const float* __restrict__ Wq, const float* __restrict__ bq,
    const float* __restrict__ Wk, const float* __restrict__ bk,
    float* __restrict__ e_out, float* __restrict__ q_out, float* __restrict__ kT_out)
{
    const int row0 = blockIdx.x << 3;
    const int tid = threadIdx.x;
    const int wid = tid >> 6, lane = tid & 63;

    __shared__ float fr[8][INDIM];
    __shared__ float th4[8][HID];
    __shared__ float ee4[4][DMODEL];
    __shared__ float part4[4][4][DMODEL];
    __shared__ float partk4[4][4][DMODEL];
    __shared__ float wred[4][8][2];

    { int r = tid >> 6, i = tid & 63;
      fr[r][i]     = fps[(row0 + r) * INDIM + i];
      fr[r + 4][i] = fps[(row0 + r + 4) * INDIM + i]; }
    __syncthreads();

    float h[8];
    float b1v = b1[tid];
    #pragma unroll
    for (int r = 0; r < 8; ++r) h[r] = b1v;
    for (int i = 0; i < INDIM; ++i) {
        float w = W1[i * HID + tid];
        #pragma unroll
        for (int r = 0; r < 8; ++r) h[r] = fmaf(fr[r][i], w, h[r]);
    }

    // fused sum / sum-of-squares reduction
    float s1[8], s2[8];
    #pragma unroll
    for (int r = 0; r < 8; ++r) { s1[r] = h[r]; s2[r] = h[r] * h[r]; }
    #pragma unroll
    for (int off = 1; off < 64; off <<= 1) {
        #pragma unroll
        for (int r = 0; r < 8; ++r) {
            s1[r] += __shfl_xor(s1[r], off);
            s2[r] += __shfl_xor(s2[r], off);
        }
    }
    if (lane == 0) {
        #pragma unroll
        for (int r = 0; r < 8; ++r) { wred[wid][r][0] = s1[r]; wred[wid][r][1] = s2[r]; }
    }
    __syncthreads();
    float gm = gamma[tid], bt = beta[tid];
    #pragma unroll
    for (int r = 0; r < 8; ++r) {
        float t1 = wred[0][r][0] + wred[1][r][0] + wred[2][r][0] + wred[3][r][0];
        float t2 = wred[0][r][1] + wred[1][r][1] + wred[2][r][1] + wred[3][r][1];
        float mu = t1 * (1.0f / HID);
        float var = t2 * (1.0f / HID) - mu * mu;
        float hn = (h[r] - mu) * rsqrtf(var + 1e-5f) * gm + bt;
        th4[r][tid] = tanhf(hn);
    }
    __syncthreads();

    #pragma unroll
    for (int half = 0; half < 2; ++half) {
        const int rbase = half * 4;
        { int p = tid >> 6, j = tid & 63;
          float acc[4] = {0.f, 0.f, 0.f, 0.f};
          for (int i = p * 64; i < p * 64 + 64; ++i) {
              float w = W2[i * DMODEL + j];
              #pragma unroll
              for (int r = 0; r < 4; ++r) acc[r] = fmaf(th4[rbase + r][i], w, acc[r]);
          }
          #pragma unroll
          for (int r = 0; r < 4; ++r) part4[p][r][j] = acc[r];
        }
        __syncthreads();
        { int r = tid >> 6, j = tid & 63;
          float e = part4[0][r][j] + part4[1][r][j] + part4[2][r][j] + part4[3][r][j] + b2[j];
          float eo = tanhf(e);
          int row = row0 + rbase + r;
          int s = row & (SS - 1);
          e_out[(size_t)row * DMODEL + j] = eo;
          float div = expf(-(float)(j & ~1) * 0.14391156831212787f);  // ln(10000)/64
          float ang = (float)s * div;
          float pe = (j & 1) ? cosf(ang) : sinf(ang);
          ee4[r][j] = eo + 0.05f * pe;
        }
        __syncthreads();
        { int p = tid >> 6, j = tid & 63;
          float aq[4] = {0.f,0.f,0.f,0.f}, ak[4] = {0.f,0.f,0.f,0.f};
          for (int i = p * 16; i < p * 16 + 16; ++i) {
              float wqv = Wq[i * DMODEL + j];
              float wkv = Wk[i * DMODEL + j];
              #pragma unroll
              for (int r = 0; r < 4; ++r) {
                  aq[r] = fmaf(ee4[r][i], wqv, aq[r]);
                  ak[r] = fmaf(ee4[r][i], wkv, ak[r]);
              }
          }
          #pragma unroll
          for (int r = 0; r < 4; ++r) { part4[p][r][j] = aq[r]; partk4[p][r][j] = ak[r]; }
        }
        __syncthreads();
        { int r = tid >> 6, j = tid & 63;
          float qv = part4[0][r][j] + part4[1][r][j] + part4[2][r][j] + part4[3][r][j] + bq[j];
          float kv = partk4[0][r][j] + partk4[1][r][j] + partk4[2][r][j] + partk4[3][r][j] + bk[j];
          int row = row0 + rbase + r;
          int b = row >> 9, s = row & (SS - 1);
          q_out[(size_t)row * DMODEL + j] = qv;
          kT_out[(size_t)(b * DMODEL + j) * SS + s] = kv;
        }
        __syncthreads();
    }
}

// ---------------------------------------------------------------------------
// Kernel 2: causal scores + softmax -> alpha f32 into d_out.  (unchanged)
// ---------------------------------------------------------------------------
__global__ __launch_bounds__(256) void k_attn(
    const float* __restrict__ q, const float* __restrict__ kT,
    float* __restrict__ alpha)
{
    const int blk = blockIdx.x;
    const int b = blk >> 7;
    const int t0 = (blk & 127) << 2;
    const int t3 = t0 + 3;
    const int tid = threadIdx.x;
    const int wave = tid >> 6, lane = tid & 63;

    __shared__ float qt[4 * DMODEL];
    __shared__ float redm[4][4];

    qt[tid] = q[(size_t)(b * SS + t0 + (tid >> 6)) * DMODEL + (tid & 63)];
    __syncthreads();

    const float* kTb = kT + (size_t)b * DMODEL * SS;
    const int s0 = tid, s1 = tid + 256;
    float a0[4] = {0,0,0,0}, a1[4] = {0,0,0,0};
    if (s1 <= t3) {
        for (int d = 0; d < DMODEL; ++d) {
            float k0 = kTb[d * SS + s0];
            float k1 = kTb[d * SS + s1];
            #pragma unroll
            for (int r = 0; r < 4; ++r) {
                float qv = qt[r * DMODEL + d];
                a0[r] = fmaf(qv, k0, a0[r]);
                a1[r] = fmaf(qv, k1, a1[r]);
            }
        }
    } else if (s0 <= t3) {
        for (int d = 0; d < DMODEL; ++d) {
            float k0 = kTb[d * SS + s0];
            #pragma unroll
            for (int r = 0; r < 4; ++r) a0[r] = fmaf(qt[r * DMODEL + d], k0, a0[r]);
        }
    }
    float lg0[4], lg1[4];
    #pragma unroll
    for (int r = 0; r < 4; ++r) {
        int tr = t0 + r;
        lg0[r] = (s0 <= tr) ? 0.25f * a0[r] : -INFINITY;
        lg1[r] = (s1 <= tr) ? 0.25f * a1[r] : -INFINITY;
    }
    float mr[4];
    #pragma unroll
    for (int r = 0; r < 4; ++r) {
        float m = fmaxf(lg0[r], lg1[r]);
        #pragma unroll
        for (int off = 32; off > 0; off >>= 1) m = fmaxf(m, __shfl_xor(m, off));
        if (lane == 0) redm[r][wave] = m;
    }
    __syncthreads();
    #pragma unroll
    for (int r = 0; r < 4; ++r)
        mr[r] = fmaxf(fmaxf(redm[r][0], redm[r][1]), fmaxf(redm[r][2], redm[r][3]));
    __syncthreads();
    float ex0[4], ex1[4], sr[4];
    #pragma unroll
    for (int r = 0; r < 4; ++r) {
        ex0[r] = expf(lg0[r] - mr[r]);
        ex1[r] = expf(lg1[r] - mr[r]);
        float sm = ex0[r] + ex1[r];
        #pragma unroll
        for (int off = 32; off > 0; off >>= 1) sm += __shfl_xor(sm, off);
        if (lane == 0) redm[r][wave] = sm;
    }
    __syncthreads();
    #pragma unroll
    for (int r = 0; r < 4; ++r)
        sr[r] = redm[r][0] + redm[r][1] + redm[r][2] + redm[r][3];
    #pragma unroll
    for (int r = 0; r < 4; ++r) {
        float inv = 1.0f / sr[r];
        size_t base = (size_t)(b * SS + t0 + r) * SS;
        alpha[base + s0] = ex0[r] * inv;
        alpha[base + s1] = ex1[r] * inv;
    }
}

// ---------------------------------------------------------------------------
// Kernel 3 (stage 1): per (b, s-chunk).  float4 broadcast dot loops,
// prefix-scan diagonals, register accumulators.  (unchanged from R8)
// ---------------------------------------------------------------------------
__global__ __launch_bounds__(256) void k_gpart(
    const float* __restrict__ x, const float* __restrict__ y,
    const int* __restrict__ steps, const float* __restrict__ alpha,
    float* __restrict__ part, int C, int CS)
{
    const int b = blockIdx.x / C;
    const int chunk = blockIdx.x % C;
    const int tid = threadIdx.x;
    const int lane = tid & 63, wid = tid >> 6;

    __shared__ __align__(16) float xs[288];
    __shared__ __align__(16) float ys[256];
    __shared__ float Gs[1056];        // 32x33 (pitch 33)
    __shared__ float crossL[32];
    __shared__ float wv[NT * 64];
    __shared__ int sl[64];
    __shared__ int nselS;
    __shared__ int stS[NT];
    __shared__ float redA[4][33];
    __shared__ float redB[4][33];

    if (tid < NT) stS[tid] = steps[tid];
    if (tid < 32) Gs[tid * 33 + 32] = 0.f;
    __syncthreads();

    for (int idx = tid; idx < NT * CS; idx += 256) {
        int t = idx / CS, si = idx % CS;
        float a = alpha[(size_t)(b * SS + stS[t]) * SS + chunk * CS + si];
        wv[t * 64 + si] = (a > THRESHF) ? a : 0.f;
    }
    __syncthreads();
    if (tid == 0) {
        int c = 0;
        for (int si = 0; si < CS; ++si) {
            float m = wv[si] + wv[64 + si] + wv[128 + si] + wv[192 + si] + wv[256 + si];
            if (m > 0.f) sl[c++] = si;
        }
        nselS = c;
    }
    __syncthreads();
    const int nsel = nselS;

    float acc[NT][5];
    #pragma unroll
    for (int t = 0; t < NT; ++t) {
        #pragma unroll
        for (int r = 0; r < 5; ++r) acc[t][r] = 0.f;
    }

    float rx0 = 0.f, rx1 = 0.f, ry = 0.f;
    if (nsel > 0) {
        int sg = chunk * CS + sl[0];
        const float* xr = x + (size_t)(b * SS + sg) * TXX;
        const float* yr = y + (size_t)(b * SS + sg) * TYY;
        rx0 = xr[tid];
        if (tid < 31) rx1 = xr[256 + tid];
        ry = yr[tid];
    }

    for (int i = 0; i < nsel; ++i) {
        xs[tid] = rx0;
        if (tid < 31) xs[256 + tid] = rx1;
        ys[tid] = ry;
        const int sl_cur = sl[i];
        __syncthreads();

        if (i + 1 < nsel) {
            int sg = chunk * CS + sl[i + 1];
            const float* xr = x + (size_t)(b * SS + sg) * TXX;
            const float* yr = y + (size_t)(b * SS + sg) * TYY;
            rx0 = xr[tid];
            if (tid < 31) rx1 = xr[256 + tid];
            ry = yr[tid];
        }

        { int l = tid & 31, p = tid >> 5;
          const float4* xk4 = (const float4*)(xs + (p << 5));
          const float4* yk4 = (const float4*)(ys + (p << 5));
          float c = 0.f, a = 0.f;
          #pragma unroll
          for (int j = 0; j < 8; ++j) {
              float4 xk = xk4[j];
              float4 yk = yk4[j];
              int kb = (p << 5) + (j << 2);
              float x0 = xs[kb + l],     x1 = xs[kb + 1 + l];
              float x2 = xs[kb + 2 + l], x3 = xs[kb + 3 + l];
              c = fmaf(x0, yk.x, c); a = fmaf(xk.x, x0, a);
              c = fmaf(x1, yk.y, c); a = fmaf(xk.y, x1, a);
              c = fmaf(x2, yk.z, c); a = fmaf(xk.z, x2, a);
              c = fmaf(x3, yk.w, c); a = fmaf(xk.w, x3, a);
          }
          c += __shfl_xor(c, 32);
          a += __shfl_xor(a, 32);
          if (lane < 32) { redA[wid][l] = c; redB[wid][l] = a; }
        }
        __syncthreads();

        if (tid < 32)
            crossL[tid] = redA[0][tid] + redA[1][tid] + redA[2][tid] + redA[3][tid];

        { int jj = lane & 31;
          #pragma unroll
          for (int pass = 0; pass < 4; ++pass) {
              int dd = 2 * (wid + 4 * pass) + (lane >> 5);
              float g0 = redB[0][dd] + redB[1][dd] + redB[2][dd] + redB[3][dd];
              float dlt = 0.f;
              if (jj > 0 && jj + dd < 32)
                  dlt = xs[jj + 255] * xs[jj + 255 + dd]
                      - xs[jj - 1] * xs[jj - 1 + dd];
              #pragma unroll
              for (int off = 1; off < 32; off <<= 1) {
                  float tsh = __shfl_up(dlt, off, 32);
                  if (jj >= off) dlt += tsh;
              }
              if (jj + dd < 32) {
                  float gval = g0 + dlt;
                  Gs[jj * 33 + jj + dd] = gval;
                  Gs[(jj + dd) * 33 + jj] = gval;
              }
          }
        }
        __syncthreads();

        { float g0 = Gs[tid], g1 = Gs[tid + 256], g2 = Gs[tid + 512], g3 = Gs[tid + 768];
          float g4 = (tid < 32) ? Gs[1024 + tid]
                   : ((tid < 64) ? crossL[tid - 32] : 0.f);
          #pragma unroll
          for (int t = 0; t < NT; ++t) {
              float w = wv[t * 64 + sl_cur];
              if (w > 0.f) {
                  acc[t][0] = fmaf(w, g0, acc[t][0]);
                  acc[t][1] = fmaf(w, g1, acc[t][1]);
                  acc[t][2] = fmaf(w, g2, acc[t][2]);
                  acc[t][3] = fmaf(w, g3, acc[t][3]);
                  acc[t][4] = fmaf(w, g4, acc[t][4]);
              }
          }
        }
    }

    #pragma unroll
    for (int t = 0; t < NT; ++t) {
        size_t base = (size_t)((b * NT + t) * C + chunk) * 1088;
        #pragma unroll
        for (int r = 0; r < 4; ++r) part[base + tid + 256 * r] = acc[t][r];
        if (tid < 64) part[base + 1024 + tid] = acc[t][4];
    }
}

// ---------------------------------------------------------------------------
// Kernel 3b: parallel tree-reduction of chunk partials -> gram[80][1088].
// Grid 80*5; block (g, seg): thread sums C values of one idx (4-way ILP).
// ---------------------------------------------------------------------------
__global__ __launch_bounds__(256) void k_reduce(
    const float* __restrict__ part, float* __restrict__ gram, int C)
{
    const int g = blockIdx.x / 5;
    const int seg = blockIdx.x % 5;
    const int tid = threadIdx.x;
    int idx = seg * 256 + tid;
    if (idx >= 1088) return;

    const float* pp = part + (size_t)g * C * 1088 + idx;
    float s0 = 0.f, s1 = 0.f, s2 = 0.f, s3 = 0.f;
    int ch = 0;
    for (; ch + 4 <= C; ch += 4) {
        s0 += pp[(size_t)(ch + 0) * 1088];
        s1 += pp[(size_t)(ch + 1) * 1088];
        s2 += pp[(size_t)(ch + 2) * 1088];
        s3 += pp[(size_t)(ch + 3) * 1088];
    }
    for (; ch < C; ++ch) s0 += pp[(size_t)ch * 1088];
    gram[(size_t)g * 1088 + idx] = (s0 + s1) + (s2 + s3);
}

// ---------------------------------------------------------------------------
// Kernel 4 (stage 2): per (b,t): read gram row, +ridge, register Cholesky
// (single wave, zero barriers), shuffle solves, prediction loss.
// ---------------------------------------------------------------------------
__global__ __launch_bounds__(256) void k_solve2(
    const float* __restrict__ x, const float* __restrict__ y,
    const int* __restrict__ steps, const float* __restrict__ alpha,
    const float* __restrict__ gram,
    float* __restrict__ lossbt, int* __restrict__ valid)
{
    const int g = blockIdx.x;
    const int b = g / NT, t = g % NT;
    const int tid = threadIdx.x;

    __shared__ float Af[1056];   // pitch 33
    __shared__ float zs[FILT];
    __shared__ float wt[FILT];
    __shared__ float xsr[TXX + 1];
    __shared__ float red[256];
    __shared__ int step_s;
    __shared__ int anyv;

    if (tid == 0) { step_s = steps[t]; anyv = 0; }
    __syncthreads();

    const float* row = gram + (size_t)g * 1088;
    Af[tid] = row[tid];
    Af[tid + 256] = row[tid + 256];
    Af[tid + 512] = row[tid + 512];
    Af[tid + 768] = row[tid + 768];
    if (tid < 32) Af[1024 + tid] = row[1024 + tid];
    else if (tid < 64) zs[tid - 32] = row[1024 + tid];

    { const float* arow = alpha + (size_t)(b * SS + step_s) * SS;
      if (arow[tid] > THRESHF || arow[tid + 256] > THRESHF) anyv = 1; }
    __syncthreads();
    if (tid < 32) Af[tid * 33 + tid] += RIDGEF;
    __syncthreads();

    // single-wave register Cholesky: lane i holds row i
    if (tid < 32) {
        float a[32];
        #pragma unroll
        for (int j = 0; j < 32; ++j) a[j] = Af[tid * 33 + j];
        #pragma unroll
        for (int k = 0; k < 32; ++k) {
            float akk = __shfl(a[k], k);
            float dk = sqrtf(akk);
            float ck = a[k] / dk;
            if (tid >= k) a[k] = ck;
            #pragma unroll
            for (int m = k + 1; m < 32; ++m) {
                float cm = __shfl(ck, m);
                if (tid >= m) a[m] = fmaf(-ck, cm, a[m]);
            }
        }
        #pragma unroll
        for (int j = 0; j < 32; ++j)
            if (j <= tid) Af[tid * 33 + j] = a[j];

        float zl = zs[tid];
        #pragma unroll
        for (int k = 0; k < 32; ++k) {
            float akk = __shfl(a[k], k);
            float zk = __shfl(zl, k) / akk;
            if (tid == k) zl = zk;
            else if (tid > k) zl = fmaf(-a[k], zk, zl);
        }
        #pragma unroll
        for (int k = 31; k >= 0; --k) {
            float akk = __shfl(a[k], k);
            float wk = __shfl(zl, k) / akk;
            if (tid == k) zl = wk;
            else if (tid < k) zl = fmaf(-Af[k * 33 + tid], wk, zl);
        }
        wt[tid] = zl;
    }
    __syncthreads();

    const int sstep = step_s;
    const float* xrow = x + (size_t)(b * SS + sstep) * TXX;
    for (int i = tid; i < TXX; i += 256) xsr[i] = xrow[i];
    __syncthreads();
    float pk = 0.f;
    #pragma unroll
    for (int l = 0; l < FILT; ++l) pk = fmaf(xsr[tid + l], wt[l], pk);
    float d = y[(size_t)(b * SS + sstep) * TYY + tid] - pk;
    red[tid] = d * d;
    __syncthreads();
    for (int off = 128; off > 0; off >>= 1) {
        if (tid < off) red[tid] += red[tid + off];
        __syncthreads();
    }
    if (tid == 0) {
        lossbt[g] = red[0] * (1.0f / TYY);
        valid[g] = anyv;
    }
}

// ---------------------------------------------------------------------------
// Kernel 5: final masked mean -> out[0] (f32)
// ---------------------------------------------------------------------------
__global__ __launch_bounds__(128) void k_final(
    const float* __restrict__ lossbt, const int* __restrict__ valid,
    float* __restrict__ out0)
{
    __shared__ float rs[128];
    __shared__ int rc[128];
    int tid = threadIdx.x;
    float v = 0.f; int c = 0;
    if (tid < BB * NT && valid[tid]) { v = lossbt[tid]; c = 1; }
    rs[tid] = v; rc[tid] = c;
    __syncthreads();
    for (int off = 64; off > 0; off >>= 1) {
        if (tid < off) { rs[tid] += rs[tid + off]; rc[tid] += rc[tid + off]; }
        __syncthreads();
    }
    if (tid == 0) {
        int n = rc[0] > 0 ? rc[0] : 1;
        out0[0] = rs[0] / (float)n;
    }
}

extern "C" void kernel_launch(void* const* d_in, const int* in_sizes, int n_in,
                              void* d_out, int out_size, void* d_ws, size_t ws_size,
                              hipStream_t stream)
{
    const float* fps  = (const float*)d_in[0];
    const float* x    = (const float*)d_in[1];
    const float* y    = (const float*)d_in[2];
    const int* steps  = (const int*)d_in[3];
    const float* W1   = (const float*)d_in[4];
    const float* b1   = (const float*)d_in[5];
    const float* gamma= (const float*)d_in[6];
    const float* beta = (const float*)d_in[7];
    const float* W2   = (const float*)d_in[8];
    const float* b2   = (const float*)d_in[9];
    const float* Wq   = (const float*)d_in[10];
    const float* bq   = (const float*)d_in[11];
    const float* Wk   = (const float*)d_in[12];
    const float* bk   = (const float*)d_in[13];

    // Output f32 flat: [loss(1) | alpha(B*S*S) | e_orig(B*S*D)]
    float* out   = (float*)d_out;
    float* alpha = out + 1;
    float* e_out = out + 1 + (size_t)BB * SS * SS;

    // ws: [lossbt | valid | gram(80*1088) | shared region (q/kT then part)]
    float* lossbt = (float*)d_ws;
    int*   valid  = (int*)(lossbt + 128);
    float* gram   = (float*)d_ws + 256;
    float* shreg  = gram + (size_t)BB * NT * 1088;
    float* q      = shreg;                                 // B*S*64
    float* kT     = q + (size_t)BB * SS * DMODEL;          // B*64*S
    float* part   = shreg;                                 // 80*C*1088 (aliased)

    size_t head_f = 256 + (size_t)BB * NT * 1088;
    size_t avail_f = (ws_size / 4 > head_f) ? (ws_size / 4 - head_f) : 0;
    int C = 64;
    while (C > 8 && (size_t)(BB * NT) * C * 1088 > avail_f) C >>= 1;
    int CS = SS / C;

    hipLaunchKernelGGL(k_mlp, dim3(BB * SS / 8), dim3(256), 0, stream,
                       fps, W1, b1, gamma, beta, W2, b2, Wq, bq, Wk, bk,
                       e_out, q, kT);
    hipLaunchKernelGGL(k_attn, dim3(BB * (SS / 4)), dim3(256), 0, stream,
                       q, kT, alpha);
    hipLaunchKernelGGL(k_gpart, dim3(BB * C), dim3(256), 0, stream,
                       x, y, steps, alpha, part, C, CS);
    hipLaunchKernelGGL(k_reduce, dim3(BB * NT * 5), dim3(256), 0, stream,
                       part, gram, C);
    hipLaunchKernelGGL(k_solve2, dim3(BB * NT), dim3(256), 0, stream,
                       x, y, steps, alpha, gram, lossbt, valid);
    hipLaunchKernelGGL(k_final, dim3(1), dim3(128), 0, stream, lossbt, valid, out);
}

// Round 10
// 200.199 us; speedup vs baseline: 3.2953x; 1.0421x over previous
//
#include <hip/hip_runtime.h>
#include <hip/hip_bf16.h>
#include <math.h>

#define BB 16
#define SS 512
#define INDIM 64
#define DMODEL 64
#define HID 256
#define FILT 32
#define TYY 256
#define TXX 287
#define NT 5
#define RIDGEF 0.01f
#define THRESHF 0.005f
#define GRAMN 1088              // per-(b,t) accumulator row: 1056 pitch-33 gram + 32 cross
#define GRAMTOT (BB * NT * GRAMN)   // 87040

// ---------------------------------------------------------------------------
// Kernel 1: fused MLP -> LN -> tanh -> W2 -> tanh (e_orig) -> +pos-enc -> q,kT.
// 8 rows/block.  Side-job: blocks 0..339 zero gram (256 floats each);
// block 340 zeros the atomic counters.  (gram not read until k_gpart.)
// ---------------------------------------------------------------------------
__global__ __launch_bounds__(256) void k_mlp(
    const float* __restrict__ fps, const float* __restrict__ W1, const float* __restrict__ b1,
    const float* __restrict__ gamma, const float* __restrict__ beta,
    const float* __restrict__ W2, const float* __restrict__ b2,
    const float* __restrict__ Wq, const float* __restrict__ bq,
    const float* __restrict__ Wk, const float* __restrict__ bk,
    float* __restrict__ e_out, float* __restrict__ q_out, float* __restrict__ kT_out,
    float* __restrict__ gram, int* __restrict__ ctrs)
{
    const int row0 = blockIdx.x << 3;
    const int tid = threadIdx.x;
    const int wid = tid >> 6, lane = tid & 63;

    // side-job: zero gram + counters (stream-ordered before k_gpart)
    if (blockIdx.x < GRAMTOT / 256) {
        gram[(size_t)blockIdx.x * 256 + tid] = 0.f;
    } else if (blockIdx.x == GRAMTOT / 256 && tid < 4) {
        ctrs[tid] = 0;   // [0]=done_ctr [1]=valid_cnt [2]=loss_sum(0.0f bits) [3]=pad
    }

    __shared__ float fr[8][INDIM];
    __shared__ float th4[8][HID];
    __shared__ float ee4[4][DMODEL];
    __shared__ float part4[4][4][DMODEL];
    __shared__ float partk4[4][4][DMODEL];
    __shared__ float wred[4][8][2];

    { int r = tid >> 6, i = tid & 63;
      fr[r][i]     = fps[(row0 + r) * INDIM + i];
      fr[r + 4][i] = fps[(row0 + r + 4) * INDIM + i]; }
    __syncthreads();

    float h[8];
    float b1v = b1[tid];
    #pragma unroll
    for (int r = 0; r < 8; ++r) h[r] = b1v;
    for (int i = 0; i < INDIM; ++i) {
        float w = W1[i * HID + tid];
        #pragma unroll
        for (int r = 0; r < 8; ++r) h[r] = fmaf(fr[r][i], w, h[r]);
    }

    float s1[8], s2[8];
    #pragma unroll
    for (int r = 0; r < 8; ++r) { s1[r] = h[r]; s2[r] = h[r] * h[r]; }
    #pragma unroll
    for (int off = 1; off < 64; off <<= 1) {
        #pragma unroll
        for (int r = 0; r < 8; ++r) {
            s1[r] += __shfl_xor(s1[r], off);
            s2[r] += __shfl_xor(s2[r], off);
        }
    }
    if (lane == 0) {
        #pragma unroll
        for (int r = 0; r < 8; ++r) { wred[wid][r][0] = s1[r]; wred[wid][r][1] = s2[r]; }
    }
    __syncthreads();
    float gm = gamma[tid], bt = beta[tid];
    #pragma unroll
    for (int r = 0; r < 8; ++r) {
        float t1 = wred[0][r][0] + wred[1][r][0] + wred[2][r][0] + wred[3][r][0];
        float t2 = wred[0][r][1] + wred[1][r][1] + wred[2][r][1] + wred[3][r][1];
        float mu = t1 * (1.0f / HID);
        float var = t2 * (1.0f / HID) - mu * mu;
        float hn = (h[r] - mu) * rsqrtf(var + 1e-5f) * gm + bt;
        th4[r][tid] = tanhf(hn);
    }
    __syncthreads();

    #pragma unroll
    for (int half = 0; half < 2; ++half) {
        const int rbase = half * 4;
        { int p = tid >> 6, j = tid & 63;
          float acc[4] = {0.f, 0.f, 0.f, 0.f};
          for (int i = p * 64; i < p * 64 + 64; ++i) {
              float w = W2[i * DMODEL + j];
              #pragma unroll
              for (int r = 0; r < 4; ++r) acc[r] = fmaf(th4[rbase + r][i], w, acc[r]);
          }
          #pragma unroll
          for (int r = 0; r < 4; ++r) part4[p][r][j] = acc[r];
        }
        __syncthreads();
        { int r = tid >> 6, j = tid & 63;
          float e = part4[0][r][j] + part4[1][r][j] + part4[2][r][j] + part4[3][r][j] + b2[j];
          float eo = tanhf(e);
          int row = row0 + rbase + r;
          int s = row & (SS - 1);
          e_out[(size_t)row * DMODEL + j] = eo;
          float div = expf(-(float)(j & ~1) * 0.14391156831212787f);  // ln(10000)/64
          float ang = (float)s * div;
          float pe = (j & 1) ? cosf(ang) : sinf(ang);
          ee4[r][j] = eo + 0.05f * pe;
        }
        __syncthreads();
        { int p = tid >> 6, j = tid & 63;
          float aq[4] = {0.f,0.f,0.f,0.f}, ak[4] = {0.f,0.f,0.f,0.f};
          for (int i = p * 16; i < p * 16 + 16; ++i) {
              float wqv = Wq[i * DMODEL + j];
              float wkv = Wk[i * DMODEL + j];
              #pragma unroll
              for (int r = 0; r < 4; ++r) {
                  aq[r] = fmaf(ee4[r][i], wqv, aq[r]);
                  ak[r] = fmaf(ee4[r][i], wkv, ak[r]);
              }
          }
          #pragma unroll
          for (int r = 0; r < 4; ++r) { part4[p][r][j] = aq[r]; partk4[p][r][j] = ak[r]; }
        }
        __syncthreads();
        { int r = tid >> 6, j = tid & 63;
          float qv = part4[0][r][j] + part4[1][r][j] + part4[2][r][j] + part4[3][r][j] + bq[j];
          float kv = partk4[0][r][j] + partk4[1][r][j] + partk4[2][r][j] + partk4[3][r][j] + bk[j];
          int row = row0 + rbase + r;
          int b = row >> 9, s = row & (SS - 1);
          q_out[(size_t)row * DMODEL + j] = qv;
          kT_out[(size_t)(b * DMODEL + j) * SS + s] = kv;
        }
        __syncthreads();
    }
}

// ---------------------------------------------------------------------------
// Kernel 2: causal scores + softmax -> alpha f32 into d_out.  (unchanged)
// ---------------------------------------------------------------------------
__global__ __launch_bounds__(256) void k_attn(
    const float* __restrict__ q, const float* __restrict__ kT,
    float* __restrict__ alpha)
{
    const int blk = blockIdx.x;
    const int b = blk >> 7;
    const int t0 = (blk & 127) << 2;
    const int t3 = t0 + 3;
    const int tid = threadIdx.x;
    const int wave = tid >> 6, lane = tid & 63;

    __shared__ float qt[4 * DMODEL];
    __shared__ float redm[4][4];

    qt[tid] = q[(size_t)(b * SS + t0 + (tid >> 6)) * DMODEL + (tid & 63)];
    __syncthreads();

    const float* kTb = kT + (size_t)b * DMODEL * SS;
    const int s0 = tid, s1 = tid + 256;
    float a0[4] = {0,0,0,0}, a1[4] = {0,0,0,0};
    if (s1 <= t3) {
        for (int d = 0; d < DMODEL; ++d) {
            float k0 = kTb[d * SS + s0];
            float k1 = kTb[d * SS + s1];
            #pragma unroll
            for (int r = 0; r < 4; ++r) {
                float qv = qt[r * DMODEL + d];
                a0[r] = fmaf(qv, k0, a0[r]);
                a1[r] = fmaf(qv, k1, a1[r]);
            }
        }
    } else if (s0 <= t3) {
        for (int d = 0; d < DMODEL; ++d) {
            float k0 = kTb[d * SS + s0];
            #pragma unroll
            for (int r = 0; r < 4; ++r) a0[r] = fmaf(qt[r * DMODEL + d], k0, a0[r]);
        }
    }
    float lg0[4], lg1[4];
    #pragma unroll
    for (int r = 0; r < 4; ++r) {
        int tr = t0 + r;
        lg0[r] = (s0 <= tr) ? 0.25f * a0[r] : -INFINITY;
        lg1[r] = (s1 <= tr) ? 0.25f * a1[r] : -INFINITY;
    }
    float mr[4];
    #pragma unroll
    for (int r = 0; r < 4; ++r) {
        float m = fmaxf(lg0[r], lg1[r]);
        #pragma unroll
        for (int off = 32; off > 0; off >>= 1) m = fmaxf(m, __shfl_xor(m, off));
        if (lane == 0) redm[r][wave] = m;
    }
    __syncthreads();
    #pragma unroll
    for (int r = 0; r < 4; ++r)
        mr[r] = fmaxf(fmaxf(redm[r][0], redm[r][1]), fmaxf(redm[r][2], redm[r][3]));
    __syncthreads();
    float ex0[4], ex1[4], sr[4];
    #pragma unroll
    for (int r = 0; r < 4; ++r) {
        ex0[r] = expf(lg0[r] - mr[r]);
        ex1[r] = expf(lg1[r] - mr[r]);
        float sm = ex0[r] + ex1[r];
        #pragma unroll
        for (int off = 32; off > 0; off >>= 1) sm += __shfl_xor(sm, off);
        if (lane == 0) redm[r][wave] = sm;
    }
    __syncthreads();
    #pragma unroll
    for (int r = 0; r < 4; ++r)
        sr[r] = redm[r][0] + redm[r][1] + redm[r][2] + redm[r][3];
    #pragma unroll
    for (int r = 0; r < 4; ++r) {
        float inv = 1.0f / sr[r];
        size_t base = (size_t)(b * SS + t0 + r) * SS;
        alpha[base + s0] = ex0[r] * inv;
        alpha[base + s1] = ex1[r] * inv;
    }
}

// ---------------------------------------------------------------------------
// Kernel 3: per (b, s-chunk); float4 dot loops, prefix-scan diagonals,
// register acc; ballot-compacted selection; atomicAdd straight into gram
// (skipping t's with no selected s in this chunk).
// ---------------------------------------------------------------------------
__global__ __launch_bounds__(256) void k_gpart(
    const float* __restrict__ x, const float* __restrict__ y,
    const int* __restrict__ steps, const float* __restrict__ alpha,
    float* __restrict__ gram, int C, int CS)
{
    const int b = blockIdx.x / C;
    const int chunk = blockIdx.x % C;
    const int tid = threadIdx.x;
    const int lane = tid & 63, wid = tid >> 6;

    __shared__ __align__(16) float xs[288];
    __shared__ __align__(16) float ys[256];
    __shared__ float Gs[1056];        // 32x33 (pitch 33)
    __shared__ float crossL[32];
    __shared__ float wv[NT * 64];
    __shared__ float wtot[NT];
    __shared__ int sl[64];
    __shared__ int nselS;
    __shared__ int stS[NT];
    __shared__ float redA[4][33];
    __shared__ float redB[4][33];

    if (tid < NT) stS[tid] = steps[tid];
    if (tid < 32) Gs[tid * 33 + 32] = 0.f;
    __syncthreads();

    for (int idx = tid; idx < NT * CS; idx += 256) {
        int t = idx / CS, si = idx % CS;
        float a = alpha[(size_t)(b * SS + stS[t]) * SS + chunk * CS + si];
        wv[t * 64 + si] = (a > THRESHF) ? a : 0.f;
    }
    __syncthreads();
    // per-t any-selected flag + ballot compaction of selected s (wave 0)
    if (tid < NT) {
        float s = 0.f;
        for (int si = 0; si < CS; ++si) s += wv[tid * 64 + si];
        wtot[tid] = s;
    }
    if (wid == 0) {
        float m = 0.f;
        if (lane < CS)
            m = wv[lane] + wv[64 + lane] + wv[128 + lane] + wv[192 + lane] + wv[256 + lane];
        unsigned long long mask = __ballot(m > 0.f);
        if (m > 0.f) {
            int pos = __popcll(mask & ((1ull << lane) - 1ull));
            sl[pos] = lane;
        }
        if (lane == 0) nselS = __popcll(mask);
    }
    __syncthreads();
    const int nsel = nselS;

    float acc[NT][5];
    #pragma unroll
    for (int t = 0; t < NT; ++t) {
        #pragma unroll
        for (int r = 0; r < 5; ++r) acc[t][r] = 0.f;
    }

    float rx0 = 0.f, rx1 = 0.f, ry = 0.f;
    if (nsel > 0) {
        int sg = chunk * CS + sl[0];
        const float* xr = x + (size_t)(b * SS + sg) * TXX;
        const float* yr = y + (size_t)(b * SS + sg) * TYY;
        rx0 = xr[tid];
        if (tid < 31) rx1 = xr[256 + tid];
        ry = yr[tid];
    }

    for (int i = 0; i < nsel; ++i) {
        xs[tid] = rx0;
        if (tid < 31) xs[256 + tid] = rx1;
        ys[tid] = ry;
        const int sl_cur = sl[i];
        __syncthreads();

        if (i + 1 < nsel) {
            int sg = chunk * CS + sl[i + 1];
            const float* xr = x + (size_t)(b * SS + sg) * TXX;
            const float* yr = y + (size_t)(b * SS + sg) * TYY;
            rx0 = xr[tid];
            if (tid < 31) rx1 = xr[256 + tid];
            ry = yr[tid];
        }

        { int l = tid & 31, p = tid >> 5;
          const float4* xk4 = (const float4*)(xs + (p << 5));
          const float4* yk4 = (const float4*)(ys + (p << 5));
          float c = 0.f, a = 0.f;
          #pragma unroll
          for (int j = 0; j < 8; ++j) {
              float4 xk = xk4[j];
              float4 yk = yk4[j];
              int kb = (p << 5) + (j << 2);
              float x0 = xs[kb + l],     x1 = xs[kb + 1 + l];
              float x2 = xs[kb + 2 + l], x3 = xs[kb + 3 + l];
              c = fmaf(x0, yk.x, c); a = fmaf(xk.x, x0, a);
              c = fmaf(x1, yk.y, c); a = fmaf(xk.y, x1, a);
              c = fmaf(x2, yk.z, c); a = fmaf(xk.z, x2, a);
              c = fmaf(x3, yk.w, c); a = fmaf(xk.w, x3, a);
          }
          c += __shfl_xor(c, 32);
          a += __shfl_xor(a, 32);
          if (lane < 32) { redA[wid][l] = c; redB[wid][l] = a; }
        }
        __syncthreads();

        if (tid < 32)
            crossL[tid] = redA[0][tid] + redA[1][tid] + redA[2][tid] + redA[3][tid];

        { int jj = lane & 31;
          #pragma unroll
          for (int pass = 0; pass < 4; ++pass) {
              int dd = 2 * (wid + 4 * pass) + (lane >> 5);
              float g0 = redB[0][dd] + redB[1][dd] + redB[2][dd] + redB[3][dd];
              float dlt = 0.f;
              if (jj > 0 && jj + dd < 32)
                  dlt = xs[jj + 255] * xs[jj + 255 + dd]
                      - xs[jj - 1] * xs[jj - 1 + dd];
              #pragma unroll
              for (int off = 1; off < 32; off <<= 1) {
                  float tsh = __shfl_up(dlt, off, 32);
                  if (jj >= off) dlt += tsh;
              }
              if (jj + dd < 32) {
                  float gval = g0 + dlt;
                  Gs[jj * 33 + jj + dd] = gval;
                  Gs[(jj + dd) * 33 + jj] = gval;
              }
          }
        }
        __syncthreads();

        { float g0 = Gs[tid], g1 = Gs[tid + 256], g2 = Gs[tid + 512], g3 = Gs[tid + 768];
          float g4 = (tid < 32) ? Gs[1024 + tid]
                   : ((tid < 64) ? crossL[tid - 32] : 0.f);
          #pragma unroll
          for (int t = 0; t < NT; ++t) {
              float w = wv[t * 64 + sl_cur];
              if (w > 0.f) {
                  acc[t][0] = fmaf(w, g0, acc[t][0]);
                  acc[t][1] = fmaf(w, g1, acc[t][1]);
                  acc[t][2] = fmaf(w, g2, acc[t][2]);
                  acc[t][3] = fmaf(w, g3, acc[t][3]);
                  acc[t][4] = fmaf(w, g4, acc[t][4]);
              }
          }
        }
    }

    // merge into global gram via atomics, skipping inactive t's
    #pragma unroll
    for (int t = 0; t < NT; ++t) {
        if (wtot[t] > 0.f) {
            float* gr = gram + (size_t)(b * NT + t) * GRAMN;
            #pragma unroll
            for (int r = 0; r < 4; ++r) atomicAdd(&gr[tid + 256 * r], acc[t][r]);
            if (tid < 64) atomicAdd(&gr[1024 + tid], acc[t][4]);
        }
    }
}

// ---------------------------------------------------------------------------
// Kernel 4: per (b,t): read gram row, +ridge, single-wave register Cholesky
// (zero barriers) + shuffle solves, prediction loss; masked-mean via atomics
// with last-block finalization -> out[0].
// ---------------------------------------------------------------------------
__global__ __launch_bounds__(256) void k_solve2(
    const float* __restrict__ x, const float* __restrict__ y,
    const int* __restrict__ steps, const float* __restrict__ alpha,
    const float* __restrict__ gram,
    int* __restrict__ ctrs, float* __restrict__ out0)
{
    const int g = blockIdx.x;
    const int b = g / NT, t = g % NT;
    const int tid = threadIdx.x;

    __shared__ float Af[1056];   // pitch 33
    __shared__ float zs[FILT];
    __shared__ float wt[FILT];
    __shared__ float xsr[TXX + 1];
    __shared__ float red[256];
    __shared__ int step_s;
    __shared__ int anyv;

    if (tid == 0) { step_s = steps[t]; anyv = 0; }
    __syncthreads();

    const float* row = gram + (size_t)g * GRAMN;
    Af[tid] = row[tid];
    Af[tid + 256] = row[tid + 256];
    Af[tid + 512] = row[tid + 512];
    Af[tid + 768] = row[tid + 768];
    if (tid < 32) Af[1024 + tid] = row[1024 + tid];
    else if (tid < 64) zs[tid - 32] = row[1024 + tid];

    { const float* arow = alpha + (size_t)(b * SS + step_s) * SS;
      if (arow[tid] > THRESHF || arow[tid + 256] > THRESHF) anyv = 1; }
    __syncthreads();
    if (tid < 32) Af[tid * 33 + tid] += RIDGEF;
    __syncthreads();

    if (tid < 32) {
        float a[32];
        #pragma unroll
        for (int j = 0; j < 32; ++j) a[j] = Af[tid * 33 + j];
        #pragma unroll
        for (int k = 0; k < 32; ++k) {
            float akk = __shfl(a[k], k);
            float dk = sqrtf(akk);
            float ck = a[k] / dk;
            if (tid >= k) a[k] = ck;
            #pragma unroll
            for (int m = k + 1; m < 32; ++m) {
                float cm = __shfl(ck, m);
                if (tid >= m) a[m] = fmaf(-ck, cm, a[m]);
            }
        }
        #pragma unroll
        for (int j = 0; j < 32; ++j)
            if (j <= tid) Af[tid * 33 + j] = a[j];

        float zl = zs[tid];
        #pragma unroll
        for (int k = 0; k < 32; ++k) {
            float akk = __shfl(a[k], k);
            float zk = __shfl(zl, k) / akk;
            if (tid == k) zl = zk;
            else if (tid > k) zl = fmaf(-a[k], zk, zl);
        }
        #pragma unroll
        for (int k = 31; k >= 0; --k) {
            float akk = __shfl(a[k], k);
            float wk = __shfl(zl, k) / akk;
            if (tid == k) zl = wk;
            else if (tid < k) zl = fmaf(-Af[k * 33 + tid], wk, zl);
        }
        wt[tid] = zl;
    }
    __syncthreads();

    const int sstep = step_s;
    const float* xrow = x + (size_t)(b * SS + sstep) * TXX;
    for (int i = tid; i < TXX; i += 256) xsr[i] = xrow[i];
    __syncthreads();
    float pk = 0.f;
    #pragma unroll
    for (int l = 0; l < FILT; ++l) pk = fmaf(xsr[tid + l], wt[l], pk);
    float d = y[(size_t)(b * SS + sstep) * TYY + tid] - pk;
    red[tid] = d * d;
    __syncthreads();
    for (int off = 128; off > 0; off >>= 1) {
        if (tid < off) red[tid] += red[tid + off];
        __syncthreads();
    }
    if (tid == 0) {
        float lossval = red[0] * (1.0f / TYY);
        float* loss_sum = (float*)(ctrs + 2);
        if (anyv) {
            atomicAdd(loss_sum, lossval);
            atomicAdd(&ctrs[1], 1);
        }
        __threadfence();
        int prev = atomicAdd(&ctrs[0], 1);
        if (prev == BB * NT - 1) {
            float s = atomicAdd(loss_sum, 0.0f);     // atomic read (device-coherent)
            int c = atomicAdd(&ctrs[1], 0);
            out0[0] = s / (float)(c > 0 ? c : 1);
        }
    }
}

extern "C" void kernel_launch(void* const* d_in, const int* in_sizes, int n_in,
                              void* d_out, int out_size, void* d_ws, size_t ws_size,
                              hipStream_t stream)
{
    const float* fps  = (const float*)d_in[0];
    const float* x    = (const float*)d_in[1];
    const float* y    = (const float*)d_in[2];
    const int* steps  = (const int*)d_in[3];
    const float* W1   = (const float*)d_in[4];
    const float* b1   = (const float*)d_in[5];
    const float* gamma= (const float*)d_in[6];
    const float* beta = (const float*)d_in[7];
    const float* W2   = (const float*)d_in[8];
    const float* b2   = (const float*)d_in[9];
    const float* Wq   = (const float*)d_in[10];
    const float* bq   = (const float*)d_in[11];
    const float* Wk   = (const float*)d_in[12];
    const float* bk   = (const float*)d_in[13];

    // Output f32 flat: [loss(1) | alpha(B*S*S) | e_orig(B*S*D)]
    float* out   = (float*)d_out;
    float* alpha = out + 1;
    float* e_out = out + 1 + (size_t)BB * SS * SS;

    // ws: [gram(80*1088) | ctrs(4 int) | q | kT]
    float* gram = (float*)d_ws;
    int*   ctrs = (int*)(gram + GRAMTOT);
    float* q    = (float*)(ctrs + 4);
    float* kT   = q + (size_t)BB * SS * DMODEL;

    const int C = 64, CS = SS / 64;

    hipLaunchKernelGGL(k_mlp, dim3(BB * SS / 8), dim3(256), 0, stream,
                       fps, W1, b1, gamma, beta, W2, b2, Wq, bq, Wk, bk,
                       e_out, q, kT, gram, ctrs);
    hipLaunchKernelGGL(k_attn, dim3(BB * (SS / 4)), dim3(256), 0, stream,
                       q, kT, alpha);
    hipLaunchKernelGGL(k_gpart, dim3(BB * C), dim3(256), 0, stream,
                       x, y, steps, alpha, gram, C, CS);
    hipLaunchKernelGGL(k_solve2, dim3(BB * NT), dim3(256), 0, stream,
                       x, y, steps, alpha, gram, ctrs, out);
}